// Round 2
// baseline (12584.931 us; speedup 1.0000x reference)
//
#include <hip/hip_runtime.h>
#include <math.h>

// ---------------------------------------------------------------------------
// Encoder: reflectpad+7x7 conv -> 4x (3x3 s2 conv) -> 4x (3x3 s2 convT)
//          -> reflectpad+7x7 conv + tanh -> masked instance-average pooling.
// InstanceNorm+ReLU fused into the NEXT conv's LDS staging load.
// fp32 compute (no fp32 MFMA on CDNA4); fp16 activation storage to keep the
// workspace at ~201 MB (A=134MB, B=67MB) and halve activation HBM traffic.
// ---------------------------------------------------------------------------

typedef _Float16 half_t;
typedef __attribute__((ext_vector_type(8))) _Float16 half8;

static __device__ __forceinline__ float xform(float v, float m, float r) {
  v = (v - m) * r;
  return v > 0.f ? v : 0.f;
}

// ---------------- conv0: reflect pad 3, 7x7, 3 -> 64 ------------------------
// grid: (4 cout-groups of 16, 1024 tiles, 4 batch), block 256 (16x16 tile)
__global__ __launch_bounds__(256) void conv0_kernel(
    const float* __restrict__ x, const float* __restrict__ w,
    const float* __restrict__ bias, half_t* __restrict__ out)
{
  const int H = 512, W = 512, CIN = 3;
  __shared__ float s_in[3][22][22];
  __shared__ float4 s_w[3 * 49][4];   // [ci*49+k][co/4] -> 16 couts
  const int cog = blockIdx.x, tile = blockIdx.y, b = blockIdx.z;
  const int tx0 = (tile & 31) << 4, ty0 = (tile >> 5) << 4;
  const int tid = threadIdx.x, tx = tid & 15, ty = tid >> 4;

  for (int idx = tid; idx < CIN * 49 * 16; idx += 256) {
    int j = idx & 15, r = idx >> 4;             // r = ci*49 + k
    ((float*)s_w)[r * 16 + j] = w[(cog * 16 + j) * (CIN * 49) + r];
  }
  for (int idx = tid; idx < CIN * 22 * 22; idx += 256) {
    int ci = idx / 484, rr = idx % 484;
    int iy = rr / 22, ix = rr % 22;
    int gy = ty0 + iy - 3, gx = tx0 + ix - 3;
    gy = gy < 0 ? -gy : (gy >= H ? 2 * H - 2 - gy : gy);
    gx = gx < 0 ? -gx : (gx >= W ? 2 * W - 2 - gx : gx);
    s_in[ci][iy][ix] = x[((size_t)(b * CIN + ci) * H + gy) * W + gx];
  }
  __syncthreads();

  float acc[16];
#pragma unroll
  for (int j = 0; j < 16; ++j) acc[j] = 0.f;

#pragma unroll
  for (int ci = 0; ci < 3; ++ci)
    for (int ky = 0; ky < 7; ++ky)
#pragma unroll
      for (int kx = 0; kx < 7; ++kx) {
        float v = s_in[ci][ty + ky][tx + kx];
        int r = (ci * 7 + ky) * 7 + kx;
#pragma unroll
        for (int q = 0; q < 4; ++q) {
          float4 wv = s_w[r][q];
          acc[q * 4 + 0] += v * wv.x;
          acc[q * 4 + 1] += v * wv.y;
          acc[q * 4 + 2] += v * wv.z;
          acc[q * 4 + 3] += v * wv.w;
        }
      }
  const int oy = ty0 + ty, ox = tx0 + tx;
#pragma unroll
  for (int j = 0; j < 16; ++j) {
    int co = cog * 16 + j;
    out[((size_t)(b * 64 + co) * H + oy) * W + ox] = (half_t)(acc[j] + bias[co]);
  }
}

// ---------------- per-(b,c) mean / rstd (fp16 input) ------------------------
__global__ __launch_bounds__(256) void stats_kernel(
    const half_t* __restrict__ x, int N, float* __restrict__ mean,
    float* __restrict__ rstd)
{
  const half8* p = (const half8*)(x + (size_t)blockIdx.x * N);
  const int n8 = N >> 3;
  float s = 0.f, s2 = 0.f;
  for (int i = threadIdx.x; i < n8; i += 256) {
    half8 v = p[i];
#pragma unroll
    for (int j = 0; j < 8; ++j) {
      float f = (float)v[j];
      s += f; s2 += f * f;
    }
  }
#pragma unroll
  for (int off = 32; off > 0; off >>= 1) {
    s += __shfl_down(s, off);
    s2 += __shfl_down(s2, off);
  }
  __shared__ float ls[4], ls2[4];
  const int wv = threadIdx.x >> 6;
  if ((threadIdx.x & 63) == 0) { ls[wv] = s; ls2[wv] = s2; }
  __syncthreads();
  if (threadIdx.x == 0) {
    float S = ls[0] + ls[1] + ls[2] + ls[3];
    float S2 = ls2[0] + ls2[1] + ls2[2] + ls2[3];
    float m = S / (float)N;
    float var = S2 / (float)N - m * m;
    mean[blockIdx.x] = m;
    rstd[blockIdx.x] = rsqrtf(var + 1e-5f);
  }
}

// ---------------- down: 3x3 stride2 pad1, norm+relu fused on load -----------
// grid: (Cout/8, (OH/16)^2, 4), block 256
__global__ __launch_bounds__(256) void down_kernel(
    const half_t* __restrict__ in, const float* __restrict__ w,
    const float* __restrict__ bias, const float* __restrict__ mean,
    const float* __restrict__ rstd, half_t* __restrict__ out,
    int Cin, int Cout, int IH, int IW)
{
  const int OH = IH >> 1, OW = IW >> 1;
  __shared__ float s_in[4][33][33];
  __shared__ float4 s_w[4][9][2];    // [ci][k][co/4] -> 8 couts
  const int cog = blockIdx.x, b = blockIdx.z;
  const int ntx = OW >> 4;
  const int tx0 = (blockIdx.y % ntx) << 4, ty0 = (blockIdx.y / ntx) << 4;
  const int tid = threadIdx.x, tx = tid & 15, ty = tid >> 4;
  const int iy0 = 2 * ty0 - 1, ix0 = 2 * tx0 - 1;

  float acc[8];
#pragma unroll
  for (int j = 0; j < 8; ++j) acc[j] = 0.f;

  for (int c0 = 0; c0 < Cin; c0 += 4) {
    __syncthreads();
    for (int idx = tid; idx < 4 * 33 * 33; idx += 256) {
      int ci = idx / 1089, rr = idx % 1089;
      int iy = rr / 33, ix = rr % 33;
      int gy = iy0 + iy, gx = ix0 + ix;
      float v = 0.f;
      if ((unsigned)gy < (unsigned)IH && (unsigned)gx < (unsigned)IW) {
        int cc = c0 + ci;
        v = (float)in[((size_t)(b * Cin + cc) * IH + gy) * IW + gx];
        v = xform(v, mean[b * Cin + cc], rstd[b * Cin + cc]);
      }
      s_in[ci][iy][ix] = v;
    }
    for (int idx = tid; idx < 4 * 9 * 8; idx += 256) {
      int j = idx & 7, r = idx >> 3;          // r = ci*9 + k
      int ci = r / 9, k = r % 9;
      ((float*)s_w)[(ci * 9 + k) * 8 + j] =
          w[((size_t)(cog * 8 + j) * Cin + c0 + ci) * 9 + k];
    }
    __syncthreads();
#pragma unroll
    for (int ci = 0; ci < 4; ++ci)
#pragma unroll
      for (int k = 0; k < 9; ++k) {
        const int ky = k / 3, kx = k % 3;
        float v = s_in[ci][2 * ty + ky][2 * tx + kx];
        float4 w0 = s_w[ci][k][0], w1 = s_w[ci][k][1];
        acc[0] += v * w0.x; acc[1] += v * w0.y;
        acc[2] += v * w0.z; acc[3] += v * w0.w;
        acc[4] += v * w1.x; acc[5] += v * w1.y;
        acc[6] += v * w1.z; acc[7] += v * w1.w;
      }
  }
  const int oy = ty0 + ty, ox = tx0 + tx;
#pragma unroll
  for (int j = 0; j < 8; ++j) {
    int co = cog * 8 + j;
    out[((size_t)(b * Cout + co) * OH + oy) * OW + ox] = (half_t)(acc[j] + bias[co]);
  }
}

// ---------------- up: convT k3 s2 p1 op1 via parity classes ------------------
// One block computes a 32x32 output region (all 4 parity classes).
// grid: (Cout/8, (OH/32)^2, 4), block 256
__global__ __launch_bounds__(256) void up_kernel(
    const half_t* __restrict__ in, const float* __restrict__ w,
    const float* __restrict__ bias, const float* __restrict__ mean,
    const float* __restrict__ rstd, half_t* __restrict__ out,
    int Cin, int Cout, int IH, int IW)
{
  const int OH = IH << 1, OW = IW << 1;
  __shared__ float s_in[8][17][17];
  __shared__ float4 s_w[8][9][2];
  const int cog = blockIdx.x, b = blockIdx.z;
  const int ntx = OW >> 5;
  const int tx0 = (blockIdx.y % ntx) << 5, ty0 = (blockIdx.y / ntx) << 5;
  const int tid = threadIdx.x, tx = tid & 15, ty = tid >> 4;
  const int iyb = ty0 >> 1, ixb = tx0 >> 1;

  float acc[4][8];
#pragma unroll
  for (int c = 0; c < 4; ++c)
#pragma unroll
    for (int j = 0; j < 8; ++j) acc[c][j] = 0.f;

  for (int c0 = 0; c0 < Cin; c0 += 8) {
    __syncthreads();
    for (int idx = tid; idx < 8 * 17 * 17; idx += 256) {
      int ci = idx / 289, rr = idx % 289;
      int iy = rr / 17, ix = rr % 17;
      int gy = iyb + iy, gx = ixb + ix;
      float v = 0.f;
      if (gy < IH && gx < IW) {
        int cc = c0 + ci;
        v = (float)in[((size_t)(b * Cin + cc) * IH + gy) * IW + gx];
        v = xform(v, mean[b * Cin + cc], rstd[b * Cin + cc]);
      }
      s_in[ci][iy][ix] = v;
    }
    for (int idx = tid; idx < 8 * 9 * 8; idx += 256) {
      int j = idx & 7, r = idx >> 3;          // r = ci*9 + k
      int ci = r / 9, k = r % 9;
      // torch ConvT layout: w[Cin][Cout][3][3]
      ((float*)s_w)[(ci * 9 + k) * 8 + j] =
          w[((size_t)(c0 + ci) * Cout + cog * 8 + j) * 9 + k];
    }
    __syncthreads();
    // out(oy=2iy-1+ky). Tap (ky,kx) feeds exactly one parity class:
    // ky==1 -> even row (row=ty); ky==0 -> odd row, row=ty+1; ky==2 -> odd, row=ty.
#pragma unroll
    for (int ci = 0; ci < 8; ++ci)
#pragma unroll
      for (int k = 0; k < 9; ++k) {
        const int ky = k / 3, kx = k % 3;
        const int row = (ky == 0) ? 1 : 0;
        const int col = (kx == 0) ? 1 : 0;
        const int cls = ((ky == 1) ? 0 : 2) + ((kx == 1) ? 0 : 1);
        float v = s_in[ci][ty + row][tx + col];
        float4 w0 = s_w[ci][k][0], w1 = s_w[ci][k][1];
        acc[cls][0] += v * w0.x; acc[cls][1] += v * w0.y;
        acc[cls][2] += v * w0.z; acc[cls][3] += v * w0.w;
        acc[cls][4] += v * w1.x; acc[cls][5] += v * w1.y;
        acc[cls][6] += v * w1.z; acc[cls][7] += v * w1.w;
      }
  }
#pragma unroll
  for (int cls = 0; cls < 4; ++cls) {
    const int eyy = cls >> 1, exx = cls & 1;
    const int oy = ty0 + 2 * ty + eyy, ox = tx0 + 2 * tx + exx;
#pragma unroll
    for (int j = 0; j < 8; ++j) {
      int co = cog * 8 + j;
      out[((size_t)(b * Cout + co) * OH + oy) * OW + ox] = (half_t)(acc[cls][j] + bias[co]);
    }
  }
}

// ---------------- final: reflect pad 3, 7x7, 64 -> 3, tanh ------------------
// grid: (1024 tiles, 4), block 256
__global__ __launch_bounds__(256) void convf_kernel(
    const half_t* __restrict__ in, const float* __restrict__ w,
    const float* __restrict__ bias, const float* __restrict__ mean,
    const float* __restrict__ rstd, float* __restrict__ out)
{
  const int H = 512, W = 512, CIN = 64;
  __shared__ float s_in[4][22][22];
  __shared__ float4 s_w[4 * 49];     // couts padded to 4
  const int tile = blockIdx.x, b = blockIdx.y;
  const int tx0 = (tile & 31) << 4, ty0 = (tile >> 5) << 4;
  const int tid = threadIdx.x, tx = tid & 15, ty = tid >> 4;
  float acc0 = 0.f, acc1 = 0.f, acc2 = 0.f;

  for (int c0 = 0; c0 < CIN; c0 += 4) {
    __syncthreads();
    for (int idx = tid; idx < 4 * 484; idx += 256) {
      int ci = idx / 484, rr = idx % 484;
      int iy = rr / 22, ix = rr % 22;
      int gy = ty0 + iy - 3, gx = tx0 + ix - 3;
      gy = gy < 0 ? -gy : (gy >= H ? 2 * H - 2 - gy : gy);
      gx = gx < 0 ? -gx : (gx >= W ? 2 * W - 2 - gx : gx);
      int cc = c0 + ci;
      float v = (float)in[((size_t)(b * CIN + cc) * H + gy) * W + gx];
      s_in[ci][iy][ix] = xform(v, mean[b * CIN + cc], rstd[b * CIN + cc]);
    }
    for (int idx = tid; idx < 4 * 49 * 4; idx += 256) {
      int j = idx & 3, r = idx >> 2;          // r = ci*49 + k
      int ci = r / 49, k = r % 49;
      ((float*)s_w)[r * 4 + j] =
          (j < 3) ? w[((size_t)j * CIN + c0 + ci) * 49 + k] : 0.f;
    }
    __syncthreads();
#pragma unroll
    for (int ci = 0; ci < 4; ++ci)
      for (int ky = 0; ky < 7; ++ky)
#pragma unroll
        for (int kx = 0; kx < 7; ++kx) {
          float v = s_in[ci][ty + ky][tx + kx];
          float4 wv = s_w[ci * 49 + ky * 7 + kx];
          acc0 += v * wv.x; acc1 += v * wv.y; acc2 += v * wv.z;
        }
  }
  const int oy = ty0 + ty, ox = tx0 + tx;
  size_t base = (size_t)(b * 3) * H * W + (size_t)oy * W + ox;
  out[base] = tanhf(acc0 + bias[0]);
  out[base + (size_t)H * W] = tanhf(acc1 + bias[1]);
  out[base + 2 * (size_t)H * W] = tanhf(acc2 + bias[2]);
}

// ---------------- masked pooling --------------------------------------------
__global__ __launch_bounds__(256) void pool_sum_kernel(
    const float* __restrict__ f, const int* __restrict__ inst,
    float* __restrict__ P)
{
  const int N = 512 * 512;
  const int b = blockIdx.x, chunk = blockIdx.y;
  const int per = N / 32;
  const int base = chunk * per;
  float s0 = 0.f, s1 = 0.f, s2 = 0.f, c = 0.f;
  for (int i = base + threadIdx.x; i < base + per; i += 256) {
    if (inst[b * N + i] == 1) {
      c += 1.f;
      s0 += f[(size_t)(b * 3 + 0) * N + i];
      s1 += f[(size_t)(b * 3 + 1) * N + i];
      s2 += f[(size_t)(b * 3 + 2) * N + i];
    }
  }
#pragma unroll
  for (int off = 32; off > 0; off >>= 1) {
    s0 += __shfl_down(s0, off); s1 += __shfl_down(s1, off);
    s2 += __shfl_down(s2, off); c += __shfl_down(c, off);
  }
  __shared__ float red[4][4];
  int wv = threadIdx.x >> 6;
  if ((threadIdx.x & 63) == 0) {
    red[wv][0] = s0; red[wv][1] = s1; red[wv][2] = s2; red[wv][3] = c;
  }
  __syncthreads();
  if (threadIdx.x == 0) {
    float t0 = red[0][0] + red[1][0] + red[2][0] + red[3][0];
    float t1 = red[0][1] + red[1][1] + red[2][1] + red[3][1];
    float t2 = red[0][2] + red[1][2] + red[2][2] + red[3][2];
    float tc = red[0][3] + red[1][3] + red[2][3] + red[3][3];
    atomicAdd(&P[b * 4 + 0], t0);
    atomicAdd(&P[b * 4 + 1], t1);
    atomicAdd(&P[b * 4 + 2], t2);
    atomicAdd(&P[b * 4 + 3], tc);
  }
}

__global__ __launch_bounds__(256) void pool_scatter_kernel(
    const int* __restrict__ inst, const float* __restrict__ P,
    float* __restrict__ out)
{
  const int N = 512 * 512;
  int idx = blockIdx.x * 256 + threadIdx.x;
  if (idx >= 4 * N) return;
  int b = idx >> 18;
  int i = idx & (N - 1);
  bool m = inst[idx] == 1;
  float inv = 1.f / P[b * 4 + 3];
  out[(size_t)(b * 3 + 0) * N + i] = m ? P[b * 4 + 0] * inv : 0.f;
  out[(size_t)(b * 3 + 1) * N + i] = m ? P[b * 4 + 1] * inv : 0.f;
  out[(size_t)(b * 3 + 2) * N + i] = m ? P[b * 4 + 2] * inv : 0.f;
}

// ---------------------------------------------------------------------------
extern "C" void kernel_launch(void* const* d_in, const int* in_sizes, int n_in,
                              void* d_out, int out_size, void* d_ws, size_t ws_size,
                              hipStream_t stream)
{
  (void)in_sizes; (void)n_in; (void)out_size; (void)ws_size;
  const float* x    = (const float*)d_in[0];
  const int*   inst = (const int*)d_in[1];
  const float* w0   = (const float*)d_in[2];
  const float* b0   = (const float*)d_in[3];
  const float *dw[4], *db[4], *uw[4], *ub[4];
  for (int i = 0; i < 4; ++i) {
    dw[i] = (const float*)d_in[4 + 2 * i];
    db[i] = (const float*)d_in[5 + 2 * i];
    uw[i] = (const float*)d_in[12 + 2 * i];
    ub[i] = (const float*)d_in[13 + 2 * i];
  }
  const float* wf = (const float*)d_in[20];
  const float* bf = (const float*)d_in[21];

  // workspace layout (bytes):
  //   A half: 134,217,728  (67,108,864 halfs — largest activation 4x64x512x512)
  //   B half:  67,108,864  (33,554,432 halfs)
  //   F fp32:  (aliases B region for final conv output, 12.6 MB)
  //   stats:   mean 4096 f32 | rstd 4096 f32 | P 16 f32
  char* base = (char*)d_ws;
  half_t* A  = (half_t*)base;
  half_t* Bh = (half_t*)(base + 134217728);
  float*  F  = (float*)(base + 134217728);            // reuse of B after u2 dead
  float*  S_mean = (float*)(base + 134217728 + 67108864);
  float*  S_rstd = S_mean + 4096;
  float*  P      = S_rstd + 4096;

  // conv0: x -> A (raw, pre-norm); stats on A
  conv0_kernel<<<dim3(4, 1024, 4), 256, 0, stream>>>(x, w0, b0, A);
  stats_kernel<<<dim3(4 * 64), 256, 0, stream>>>(A, 512 * 512, S_mean, S_rstd);

  half_t* cur = A;
  half_t* nxt = Bh;
  int C = 64, Hh = 512;
  for (int i = 0; i < 4; ++i) {
    int OH = Hh >> 1;
    dim3 g((2 * C) / 8, (OH / 16) * (OH / 16), 4);
    down_kernel<<<g, 256, 0, stream>>>(cur, dw[i], db[i], S_mean, S_rstd, nxt,
                                       C, 2 * C, Hh, Hh);
    stats_kernel<<<dim3(4 * 2 * C), 256, 0, stream>>>(nxt, OH * OH, S_mean, S_rstd);
    half_t* t = cur; cur = nxt; nxt = t;
    C *= 2; Hh = OH;
  }
  for (int i = 0; i < 4; ++i) {
    int OH = Hh << 1;
    dim3 g((C / 2) / 8, (OH / 32) * (OH / 32), 4);
    up_kernel<<<g, 256, 0, stream>>>(cur, uw[i], ub[i], S_mean, S_rstd, nxt,
                                     C, C / 2, Hh, Hh);
    stats_kernel<<<dim3(4 * (C / 2)), 256, 0, stream>>>(nxt, OH * OH, S_mean, S_rstd);
    half_t* t = cur; cur = nxt; nxt = t;
    C /= 2; Hh = OH;
  }
  // cur = A (holds u3, 4x64x512x512 halfs). Final conv -> F (fp32), pool -> d_out.
  convf_kernel<<<dim3(1024, 4), 256, 0, stream>>>(cur, wf, bf, S_mean, S_rstd, F);
  hipMemsetAsync(P, 0, 16 * sizeof(float), stream);
  pool_sum_kernel<<<dim3(4, 32), 256, 0, stream>>>(F, inst, P);
  pool_scatter_kernel<<<dim3(4096), 256, 0, stream>>>(inst, P, (float*)d_out);
}

// Round 4
// 2677.705 us; speedup vs baseline: 4.6999x; 4.6999x over previous
//
#include <hip/hip_runtime.h>
#include <math.h>

// ---------------------------------------------------------------------------
// Encoder on MI355X.
// NHWC fp16 activations; 3x3 down/up convs as tap-wise implicit GEMM on
// mfma_f32_16x16x32_f16 (fp32 accum). InstanceNorm+ReLU fused into staging.
// conv0/convf remain fp32 direct (small share of FLOPs). Weights pre-cast to
// fp16 [tap][co][ci] into dead workspace regions each launch.
// ---------------------------------------------------------------------------

typedef _Float16 half_t;
typedef _Float16 halfx8 __attribute__((ext_vector_type(8)));
typedef _Float16 halfx4 __attribute__((ext_vector_type(4)));
typedef float floatx4 __attribute__((ext_vector_type(4)));

static __device__ __forceinline__ float xform(float v, float m, float r) {
  v = (v - m) * r;
  return v > 0.f ? v : 0.f;
}

// ---------------- weight transform: -> fp16 [tap][Cout][Cin] ----------------
// mode 0: src OIHW [Cout][Cin][3][3]; mode 1: src IOHW [Cin][Cout][3][3]
__global__ __launch_bounds__(256) void transform_w(
    const float* __restrict__ src, half_t* __restrict__ dst,
    int Cin, int Cout, int mode)
{
  int idx = blockIdx.x * 256 + threadIdx.x;
  int total = Cin * Cout * 9;
  if (idx >= total) return;
  int tap = idx % 9, t2 = idx / 9;
  int co, ci;
  if (mode == 0) { ci = t2 % Cin; co = t2 / Cin; }
  else           { co = t2 % Cout; ci = t2 / Cout; }
  dst[((size_t)tap * Cout + co) * Cin + ci] = (half_t)src[idx];
}

// ---------------- conv0: reflect pad 3, 7x7, 3 -> 64, NHWC fp16 out ---------
__global__ __launch_bounds__(256) void conv0_kernel(
    const float* __restrict__ x, const float* __restrict__ w,
    const float* __restrict__ bias, half_t* __restrict__ out)
{
  const int H = 512, W = 512, CIN = 3;
  __shared__ float s_in[3][22][22];
  __shared__ float4 s_w[3 * 49][4];
  const int cog = blockIdx.x, tile = blockIdx.y, b = blockIdx.z;
  const int tx0 = (tile & 31) << 4, ty0 = (tile >> 5) << 4;
  const int tid = threadIdx.x, tx = tid & 15, ty = tid >> 4;

  for (int idx = tid; idx < CIN * 49 * 16; idx += 256) {
    int j = idx & 15, r = idx >> 4;
    ((float*)s_w)[r * 16 + j] = w[(cog * 16 + j) * (CIN * 49) + r];
  }
  for (int idx = tid; idx < CIN * 22 * 22; idx += 256) {
    int ci = idx / 484, rr = idx % 484;
    int iy = rr / 22, ix = rr % 22;
    int gy = ty0 + iy - 3, gx = tx0 + ix - 3;
    gy = gy < 0 ? -gy : (gy >= H ? 2 * H - 2 - gy : gy);
    gx = gx < 0 ? -gx : (gx >= W ? 2 * W - 2 - gx : gx);
    s_in[ci][iy][ix] = x[((size_t)(b * CIN + ci) * H + gy) * W + gx];
  }
  __syncthreads();

  float acc[16];
#pragma unroll
  for (int j = 0; j < 16; ++j) acc[j] = 0.f;

#pragma unroll
  for (int ci = 0; ci < 3; ++ci)
    for (int ky = 0; ky < 7; ++ky)
#pragma unroll
      for (int kx = 0; kx < 7; ++kx) {
        float v = s_in[ci][ty + ky][tx + kx];
        int r = (ci * 7 + ky) * 7 + kx;
#pragma unroll
        for (int q = 0; q < 4; ++q) {
          float4 wv = s_w[r][q];
          acc[q * 4 + 0] += v * wv.x;
          acc[q * 4 + 1] += v * wv.y;
          acc[q * 4 + 2] += v * wv.z;
          acc[q * 4 + 3] += v * wv.w;
        }
      }
  const int oy = ty0 + ty, ox = tx0 + tx;
  halfx8 o0, o1;
#pragma unroll
  for (int j = 0; j < 8; ++j) {
    o0[j] = (half_t)(acc[j] + bias[cog * 16 + j]);
    o1[j] = (half_t)(acc[8 + j] + bias[cog * 16 + 8 + j]);
  }
  size_t obase = ((size_t)(b * 512 + oy) * 512 + ox) * 64 + cog * 16;
  *(halfx8*)(&out[obase]) = o0;
  *(halfx8*)(&out[obase + 8]) = o1;
}

// ---------------- stats (NHWC): partial sums + atomics ----------------------
__global__ __launch_bounds__(256) void stats_part(
    const half_t* __restrict__ x, float* __restrict__ Ssum, int C, int S)
{
  const int b = blockIdx.y, tid = threadIdx.x;
  const size_t base = (size_t)b * S * C;
  const int E8 = (S * C) >> 3;
  float s[8], s2[8];
#pragma unroll
  for (int j = 0; j < 8; ++j) { s[j] = 0.f; s2[j] = 0.f; }
  for (int i8 = blockIdx.x * 256 + tid; i8 < E8; i8 += gridDim.x * 256) {
    halfx8 v = *(const halfx8*)(x + base + (size_t)i8 * 8);
#pragma unroll
    for (int j = 0; j < 8; ++j) {
      float f = (float)v[j];
      s[j] += f; s2[j] += f * f;
    }
  }
  __shared__ float part[256][16];
#pragma unroll
  for (int j = 0; j < 8; ++j) { part[tid][j] = s[j]; part[tid][8 + j] = s2[j]; }
  __syncthreads();
  const int T = C >> 3, reps = 256 / (C >> 3);
  for (int c = tid; c < C; c += 256) {
    int r = c >> 3, j = c & 7;
    float ss = 0.f, ss2 = 0.f;
    for (int m = 0; m < reps; ++m) {
      ss += part[r + m * T][j];
      ss2 += part[r + m * T][8 + j];
    }
    atomicAdd(&Ssum[(size_t)(b * C + c) * 2], ss);
    atomicAdd(&Ssum[(size_t)(b * C + c) * 2 + 1], ss2);
  }
}

__global__ __launch_bounds__(256) void finalize_stats(
    const float* __restrict__ Ssum, float* __restrict__ mean,
    float* __restrict__ rstd, int total, float invN)
{
  int idx = blockIdx.x * 256 + threadIdx.x;
  if (idx >= total) return;
  float sm = Ssum[(size_t)idx * 2], s2 = Ssum[(size_t)idx * 2 + 1];
  float m = sm * invN;
  float var = s2 * invN - m * m;
  mean[idx] = m;
  rstd[idx] = rsqrtf(var + 1e-5f);
}

// ---------------- down: 3x3 s2 conv, MFMA implicit GEMM ---------------------
// Block 256 = 4 waves; tile: 64 spatial (4 oy x 16 ox) x 128 co.
// Wave w: co [cog*128+w*32, +32) (2 N-tiles), all 4 M-tiles.
__global__ __launch_bounds__(256) void down_mfma(
    const half_t* __restrict__ in, const half_t* __restrict__ wt,
    const float* __restrict__ bias, const float* __restrict__ mean,
    const float* __restrict__ rstd, half_t* __restrict__ out,
    int Cin, int Cout, int IH, int IW)
{
  const int OH = IH >> 1, OW = IW >> 1;
  __shared__ _Float16 sX[9 * 33 * 40];  // [y 9][x 33][ci 32 pad 40]
  const int tid = threadIdx.x;
  const int wave = tid >> 6, lane = tid & 63;
  const int ln = lane & 15, g = lane >> 4;
  const int cog = blockIdx.x, b = blockIdx.z;
  const int ntx = OW >> 4;
  const int ox0 = (blockIdx.y % ntx) << 4, oy0 = (blockIdx.y / ntx) << 2;
  const int iy0 = 2 * oy0 - 1, ix0 = 2 * ox0 - 1;
  const int coW = cog * 128 + wave * 32;
  const int q = tid & 3;

  floatx4 acc[4][2];
#pragma unroll
  for (int r = 0; r < 4; ++r)
#pragma unroll
    for (int n = 0; n < 2; ++n) acc[r][n] = floatx4{0.f, 0.f, 0.f, 0.f};

  for (int c0 = 0; c0 < Cin; c0 += 32) {
    float mq[8], rq[8];
#pragma unroll
    for (int j = 0; j < 8; ++j) {
      int cc = c0 + q * 8 + j;
      mq[j] = mean[b * Cin + cc];
      rq[j] = rstd[b * Cin + cc];
    }
    __syncthreads();
    for (int idx = tid; idx < 9 * 33 * 4; idx += 256) {
      int p = idx >> 2;
      int y = p / 33, xx = p % 33;
      int gy = iy0 + y, gx = ix0 + xx;
      halfx8 v = {0, 0, 0, 0, 0, 0, 0, 0};
      if ((unsigned)gy < (unsigned)IH && (unsigned)gx < (unsigned)IW) {
        v = *(const halfx8*)(in + ((size_t)(b * IH + gy) * IW + gx) * Cin + c0 + q * 8);
#pragma unroll
        for (int j = 0; j < 8; ++j) {
          float f = ((float)v[j] - mq[j]) * rq[j];
          v[j] = (_Float16)(f > 0.f ? f : 0.f);
        }
      }
      *(halfx8*)(&sX[(y * 33 + xx) * 40 + q * 8]) = v;
    }
    __syncthreads();
#pragma unroll
    for (int tap = 0; tap < 9; ++tap) {
      const int ky = tap / 3, kx = tap % 3;
      halfx8 wb0 = *(const halfx8*)(wt + ((size_t)tap * Cout + coW + ln) * Cin + c0 + g * 8);
      halfx8 wb1 = *(const halfx8*)(wt + ((size_t)tap * Cout + coW + 16 + ln) * Cin + c0 + g * 8);
#pragma unroll
      for (int r = 0; r < 4; ++r) {
        halfx8 a = *(const halfx8*)(&sX[((2 * r + ky) * 33 + 2 * ln + kx) * 40 + g * 8]);
        acc[r][0] = __builtin_amdgcn_mfma_f32_16x16x32_f16(a, wb0, acc[r][0], 0, 0, 0);
        acc[r][1] = __builtin_amdgcn_mfma_f32_16x16x32_f16(a, wb1, acc[r][1], 0, 0, 0);
      }
    }
  }
#pragma unroll
  for (int nt = 0; nt < 2; ++nt) {
    int co = coW + nt * 16 + ln;
    float bs = bias[co];
#pragma unroll
    for (int r = 0; r < 4; ++r)
#pragma unroll
      for (int i = 0; i < 4; ++i) {
        int oy = oy0 + r, ox = ox0 + g * 4 + i;
        out[((size_t)(b * OH + oy) * OW + ox) * Cout + co] = (half_t)(acc[r][nt][i] + bs);
      }
  }
}

// ---------------- up: convT k3 s2 p1 op1, MFMA via parity classes -----------
// Block 256 = 4 waves; tile: 256 spatial (8 oy x 32 ox) x 64 co.
// Wave w: co [cog*64+w*16, +16) (1 N-tile), 16 M-tiles (4 classes x 4 oyc).
__global__ __launch_bounds__(256) void up_mfma(
    const half_t* __restrict__ in, const half_t* __restrict__ wt,
    const float* __restrict__ bias, const float* __restrict__ mean,
    const float* __restrict__ rstd, half_t* __restrict__ out,
    int Cin, int Cout, int IH, int IW)
{
  const int OH = IH << 1, OW = IW << 1;
  __shared__ _Float16 sX[5 * 17 * 40];  // [y 5][x 17][ci 32 pad 40]
  const int tid = threadIdx.x;
  const int wave = tid >> 6, lane = tid & 63;
  const int ln = lane & 15, g = lane >> 4;
  const int cog = blockIdx.x, b = blockIdx.z;
  const int ntx = OW >> 5;
  const int ox0 = (blockIdx.y % ntx) << 5, oy0 = (blockIdx.y / ntx) << 3;
  const int iyb = oy0 >> 1, ixb = ox0 >> 1;
  const int co = cog * 64 + wave * 16 + ln;
  const int q = tid & 3;

  floatx4 acc[4][4];  // [class][oyc]
#pragma unroll
  for (int c = 0; c < 4; ++c)
#pragma unroll
    for (int r = 0; r < 4; ++r) acc[c][r] = floatx4{0.f, 0.f, 0.f, 0.f};

  for (int c0 = 0; c0 < Cin; c0 += 32) {
    float mq[8], rq[8];
#pragma unroll
    for (int j = 0; j < 8; ++j) {
      int cc = c0 + q * 8 + j;
      mq[j] = mean[b * Cin + cc];
      rq[j] = rstd[b * Cin + cc];
    }
    __syncthreads();
    for (int idx = tid; idx < 5 * 17 * 4; idx += 256) {
      int p = idx >> 2;
      int y = p / 17, xx = p % 17;
      int gy = iyb + y, gx = ixb + xx;
      halfx8 v = {0, 0, 0, 0, 0, 0, 0, 0};
      if (gy < IH && gx < IW) {
        v = *(const halfx8*)(in + ((size_t)(b * IH + gy) * IW + gx) * Cin + c0 + q * 8);
#pragma unroll
        for (int j = 0; j < 8; ++j) {
          float f = ((float)v[j] - mq[j]) * rq[j];
          v[j] = (_Float16)(f > 0.f ? f : 0.f);
        }
      }
      *(halfx8*)(&sX[(y * 17 + xx) * 40 + q * 8]) = v;
    }
    __syncthreads();
#pragma unroll
    for (int tap = 0; tap < 9; ++tap) {
      const int ky = tap / 3, kx = tap % 3;
      const int cls = ((ky == 1) ? 0 : 2) + ((kx == 1) ? 0 : 1);
      const int dy = (ky == 0) ? 1 : 0;
      const int dx = (kx == 0) ? 1 : 0;
      halfx8 wb = *(const halfx8*)(wt + ((size_t)tap * Cout + co) * Cin + c0 + g * 8);
#pragma unroll
      for (int r = 0; r < 4; ++r) {
        halfx8 a = *(const halfx8*)(&sX[((r + dy) * 17 + ln + dx) * 40 + g * 8]);
        acc[cls][r] = __builtin_amdgcn_mfma_f32_16x16x32_f16(a, wb, acc[cls][r], 0, 0, 0);
      }
    }
  }
  float bs = bias[co];
#pragma unroll
  for (int cls = 0; cls < 4; ++cls) {
    const int ey = cls >> 1, ex = cls & 1;
#pragma unroll
    for (int r = 0; r < 4; ++r)
#pragma unroll
      for (int i = 0; i < 4; ++i) {
        int oy = oy0 + 2 * r + ey;
        int ox = ox0 + 2 * (g * 4 + i) + ex;
        out[((size_t)(b * OH + oy) * OW + ox) * Cout + co] = (half_t)(acc[cls][r][i] + bs);
      }
  }
}

// ---------------- final: reflect pad 3, 7x7, 64 -> 3, tanh (NHWC in) --------
__global__ __launch_bounds__(256) void convf_kernel(
    const half_t* __restrict__ in, const float* __restrict__ w,
    const float* __restrict__ bias, const float* __restrict__ mean,
    const float* __restrict__ rstd, float* __restrict__ out)
{
  const int H = 512, W = 512, CIN = 64;
  __shared__ float s_in[4][22][22];
  __shared__ float4 s_w[4 * 49];
  const int tile = blockIdx.x, b = blockIdx.y;
  const int tx0 = (tile & 31) << 4, ty0 = (tile >> 5) << 4;
  const int tid = threadIdx.x, tx = tid & 15, ty = tid >> 4;
  float acc0 = 0.f, acc1 = 0.f, acc2 = 0.f;

  for (int c0 = 0; c0 < CIN; c0 += 4) {
    float m0 = mean[b * 64 + c0], m1 = mean[b * 64 + c0 + 1],
          m2 = mean[b * 64 + c0 + 2], m3 = mean[b * 64 + c0 + 3];
    float r0 = rstd[b * 64 + c0], r1 = rstd[b * 64 + c0 + 1],
          r2 = rstd[b * 64 + c0 + 2], r3 = rstd[b * 64 + c0 + 3];
    __syncthreads();
    for (int idx = tid; idx < 484; idx += 256) {
      int iy = idx / 22, ix = idx % 22;
      int gy = ty0 + iy - 3, gx = tx0 + ix - 3;
      gy = gy < 0 ? -gy : (gy >= H ? 2 * H - 2 - gy : gy);
      gx = gx < 0 ? -gx : (gx >= W ? 2 * W - 2 - gx : gx);
      halfx4 vv = *(const halfx4*)(in + ((size_t)(b * 512 + gy) * 512 + gx) * 64 + c0);
      s_in[0][iy][ix] = xform((float)vv[0], m0, r0);
      s_in[1][iy][ix] = xform((float)vv[1], m1, r1);
      s_in[2][iy][ix] = xform((float)vv[2], m2, r2);
      s_in[3][iy][ix] = xform((float)vv[3], m3, r3);
    }
    for (int idx = tid; idx < 4 * 49 * 4; idx += 256) {
      int j = idx & 3, r = idx >> 2;
      int ci = r / 49, k = r % 49;
      ((float*)s_w)[r * 4 + j] =
          (j < 3) ? w[((size_t)j * CIN + c0 + ci) * 49 + k] : 0.f;
    }
    __syncthreads();
#pragma unroll
    for (int ci = 0; ci < 4; ++ci)
      for (int ky = 0; ky < 7; ++ky)
#pragma unroll
        for (int kx = 0; kx < 7; ++kx) {
          float v = s_in[ci][ty + ky][tx + kx];
          float4 wv = s_w[ci * 49 + ky * 7 + kx];
          acc0 += v * wv.x; acc1 += v * wv.y; acc2 += v * wv.z;
        }
  }
  const int oy = ty0 + ty, ox = tx0 + tx;
  size_t base = (size_t)(b * 3) * H * W + (size_t)oy * W + ox;
  out[base] = tanhf(acc0 + bias[0]);
  out[base + (size_t)H * W] = tanhf(acc1 + bias[1]);
  out[base + 2 * (size_t)H * W] = tanhf(acc2 + bias[2]);
}

// ---------------- masked pooling --------------------------------------------
__global__ __launch_bounds__(256) void pool_sum_kernel(
    const float* __restrict__ f, const int* __restrict__ inst,
    float* __restrict__ P)
{
  const int N = 512 * 512;
  const int b = blockIdx.x, chunk = blockIdx.y;
  const int per = N / 32;
  const int base = chunk * per;
  float s0 = 0.f, s1 = 0.f, s2 = 0.f, c = 0.f;
  for (int i = base + threadIdx.x; i < base + per; i += 256) {
    if (inst[b * N + i] == 1) {
      c += 1.f;
      s0 += f[(size_t)(b * 3 + 0) * N + i];
      s1 += f[(size_t)(b * 3 + 1) * N + i];
      s2 += f[(size_t)(b * 3 + 2) * N + i];
    }
  }
#pragma unroll
  for (int off = 32; off > 0; off >>= 1) {
    s0 += __shfl_down(s0, off); s1 += __shfl_down(s1, off);
    s2 += __shfl_down(s2, off); c += __shfl_down(c, off);
  }
  __shared__ float red[4][4];
  int wv = threadIdx.x >> 6;
  if ((threadIdx.x & 63) == 0) {
    red[wv][0] = s0; red[wv][1] = s1; red[wv][2] = s2; red[wv][3] = c;
  }
  __syncthreads();
  if (threadIdx.x == 0) {
    float t0 = red[0][0] + red[1][0] + red[2][0] + red[3][0];
    float t1 = red[0][1] + red[1][1] + red[2][1] + red[3][1];
    float t2 = red[0][2] + red[1][2] + red[2][2] + red[3][2];
    float tc = red[0][3] + red[1][3] + red[2][3] + red[3][3];
    atomicAdd(&P[b * 4 + 0], t0);
    atomicAdd(&P[b * 4 + 1], t1);
    atomicAdd(&P[b * 4 + 2], t2);
    atomicAdd(&P[b * 4 + 3], tc);
  }
}

__global__ __launch_bounds__(256) void pool_scatter_kernel(
    const int* __restrict__ inst, const float* __restrict__ P,
    float* __restrict__ out)
{
  const int N = 512 * 512;
  int idx = blockIdx.x * 256 + threadIdx.x;
  if (idx >= 4 * N) return;
  int b = idx >> 18;
  int i = idx & (N - 1);
  bool m = inst[idx] == 1;
  float inv = 1.f / P[b * 4 + 3];
  out[(size_t)(b * 3 + 0) * N + i] = m ? P[b * 4 + 0] * inv : 0.f;
  out[(size_t)(b * 3 + 1) * N + i] = m ? P[b * 4 + 1] * inv : 0.f;
  out[(size_t)(b * 3 + 2) * N + i] = m ? P[b * 4 + 2] * inv : 0.f;
}

// ---------------------------------------------------------------------------
extern "C" void kernel_launch(void* const* d_in, const int* in_sizes, int n_in,
                              void* d_out, int out_size, void* d_ws, size_t ws_size,
                              hipStream_t stream)
{
  (void)in_sizes; (void)n_in; (void)out_size; (void)ws_size;
  const float* x    = (const float*)d_in[0];
  const int*   inst = (const int*)d_in[1];
  const float* w0   = (const float*)d_in[2];
  const float* b0   = (const float*)d_in[3];
  const float *dw[4], *db[4], *uw[4], *ub[4];
  for (int i = 0; i < 4; ++i) {
    dw[i] = (const float*)d_in[4 + 2 * i];
    db[i] = (const float*)d_in[5 + 2 * i];
    uw[i] = (const float*)d_in[12 + 2 * i];
    ub[i] = (const float*)d_in[13 + 2 * i];
  }
  const float* wf = (const float*)d_in[20];
  const float* bf = (const float*)d_in[21];

  // ---- workspace layout (total ~201.7 MB) ----
  // A:   [0, 134217728)            half, largest activation (4x512x512x64)
  // B:   [134217728, 201326592)    half; F (fp32, 12.6MB) aliases B after u3
  // SS:  [201326592, ...)          Ssum(32KB) | mean(16KB) | rstd(16KB) | P
  // WTp0/WTp1: small weight scratch (d0, u3)
  // WTA = A-tail (last 9.4MB of A), WTB = B-tail: per-layer fp16 weights,
  // written into regions that are dead at that point in the stream.
  char* base = (char*)d_ws;
  half_t* A  = (half_t*)base;
  half_t* Bh = (half_t*)(base + 134217728);
  float*  F  = (float*)(base + 134217728);
  float*  Ssum   = (float*)(base + 201326592);
  float*  S_mean = (float*)(base + 201326592 + 32768);
  float*  S_rstd = (float*)(base + 201326592 + 49152);
  float*  P      = (float*)(base + 201326592 + 65536);
  half_t* WTp0   = (half_t*)(base + 201326592 + 66560);
  half_t* WTp1   = (half_t*)(base + 201326592 + 66560 + 147456);
  half_t* WTA    = (half_t*)(base + 124780544);   // 134217728 - 9437184
  half_t* WTB    = (half_t*)(base + 191889408);   // 201326592 - 9437184

  auto XFORM = [&](const float* src, half_t* dst, int Ci, int Co, int mode) {
    int tot = Ci * Co * 9;
    transform_w<<<dim3((tot + 255) / 256), 256, 0, stream>>>(src, dst, Ci, Co, mode);
  };
  auto STATS = [&](const half_t* p, int C, int S) {
    hipMemsetAsync(Ssum, 0, 4096 * 2 * sizeof(float), stream);
    stats_part<<<dim3(128, 4), 256, 0, stream>>>(p, Ssum, C, S);
    finalize_stats<<<dim3((4 * C + 255) / 256), 256, 0, stream>>>(
        Ssum, S_mean, S_rstd, 4 * C, 1.f / (float)S);
  };

  // conv0 -> A (raw); stats
  conv0_kernel<<<dim3(4, 1024, 4), 256, 0, stream>>>(x, w0, b0, A);
  STATS(A, 64, 512 * 512);

  // d0: A(64,512) -> B(128,256)
  XFORM(dw[0], WTp0, 64, 128, 0);
  down_mfma<<<dim3(1, 1024, 4), 256, 0, stream>>>(A, WTp0, db[0], S_mean, S_rstd, Bh, 64, 128, 512, 512);
  STATS(Bh, 128, 256 * 256);
  // d1: B -> A(256,128)
  XFORM(dw[1], WTA, 128, 256, 0);
  down_mfma<<<dim3(2, 256, 4), 256, 0, stream>>>(Bh, WTA, db[1], S_mean, S_rstd, A, 128, 256, 256, 256);
  STATS(A, 256, 128 * 128);
  // d2: A -> B(512,64)
  XFORM(dw[2], WTB, 256, 512, 0);
  down_mfma<<<dim3(4, 64, 4), 256, 0, stream>>>(A, WTB, db[2], S_mean, S_rstd, Bh, 256, 512, 128, 128);
  STATS(Bh, 512, 64 * 64);
  // d3: B -> A(1024,32)
  XFORM(dw[3], WTA, 512, 1024, 0);
  down_mfma<<<dim3(8, 16, 4), 256, 0, stream>>>(Bh, WTA, db[3], S_mean, S_rstd, A, 512, 1024, 64, 64);
  STATS(A, 1024, 32 * 32);

  // u0: A(1024,32) -> B(512,64)
  XFORM(uw[0], WTB, 1024, 512, 1);
  up_mfma<<<dim3(8, 16, 4), 256, 0, stream>>>(A, WTB, ub[0], S_mean, S_rstd, Bh, 1024, 512, 32, 32);
  STATS(Bh, 512, 64 * 64);
  // u1: B -> A(256,128)
  XFORM(uw[1], WTA, 512, 256, 1);
  up_mfma<<<dim3(4, 64, 4), 256, 0, stream>>>(Bh, WTA, ub[1], S_mean, S_rstd, A, 512, 256, 64, 64);
  STATS(A, 256, 128 * 128);
  // u2: A -> B(128,256)
  XFORM(uw[2], WTA, 256, 128, 1);
  up_mfma<<<dim3(2, 256, 4), 256, 0, stream>>>(A, WTA, ub[2], S_mean, S_rstd, Bh, 256, 128, 128, 128);
  STATS(Bh, 128, 256 * 256);
  // u3: B -> A(64,512)
  XFORM(uw[3], WTp1, 128, 64, 1);
  up_mfma<<<dim3(1, 1024, 4), 256, 0, stream>>>(Bh, WTp1, ub[3], S_mean, S_rstd, A, 128, 64, 256, 256);
  STATS(A, 64, 512 * 512);

  // final conv -> F (fp32 CHW planes, aliases B), then pooling
  convf_kernel<<<dim3(1024, 4), 256, 0, stream>>>(A, wf, bf, S_mean, S_rstd, F);
  hipMemsetAsync(P, 0, 16 * sizeof(float), stream);
  pool_sum_kernel<<<dim3(4, 32), 256, 0, stream>>>(F, inst, P);
  pool_scatter_kernel<<<dim3(4096), 256, 0, stream>>>(inst, P, (float*)d_out);
}

// Round 5
// 1855.946 us; speedup vs baseline: 6.7809x; 1.4428x over previous
//
#include <hip/hip_runtime.h>
#include <math.h>

// ---------------------------------------------------------------------------
// Encoder on MI355X.
// NHWC fp16 activations; 3x3 down/up convs AND final 7x7 conv as tap-wise
// implicit GEMM on mfma_f32_16x16x32_f16 (fp32 accum). InstanceNorm+ReLU
// fused into staging. conv0 remains fp32 direct. Weights pre-cast to fp16
// [tap][co][ci] into dead workspace regions each launch.
// ---------------------------------------------------------------------------

typedef _Float16 half_t;
typedef _Float16 halfx8 __attribute__((ext_vector_type(8)));
typedef _Float16 halfx4 __attribute__((ext_vector_type(4)));
typedef float floatx4 __attribute__((ext_vector_type(4)));

static __device__ __forceinline__ float xform(float v, float m, float r) {
  v = (v - m) * r;
  return v > 0.f ? v : 0.f;
}

// ---------------- weight transform: -> fp16 [tap][Cout][Cin] ----------------
// mode 0: src OIHW [Cout][Cin][3][3]; mode 1: src IOHW [Cin][Cout][3][3]
__global__ __launch_bounds__(256) void transform_w(
    const float* __restrict__ src, half_t* __restrict__ dst,
    int Cin, int Cout, int mode)
{
  int idx = blockIdx.x * 256 + threadIdx.x;
  int total = Cin * Cout * 9;
  if (idx >= total) return;
  int tap = idx % 9, t2 = idx / 9;
  int co, ci;
  if (mode == 0) { ci = t2 % Cin; co = t2 / Cin; }
  else           { co = t2 % Cout; ci = t2 / Cout; }
  dst[((size_t)tap * Cout + co) * Cin + ci] = (half_t)src[idx];
}

// final-conv weights: src [3][64][7][7] -> dst [tap49][co16(pad0)][ci64]
__global__ __launch_bounds__(256) void transform_wf(
    const float* __restrict__ src, half_t* __restrict__ dst)
{
  int idx = blockIdx.x * 256 + threadIdx.x;
  if (idx >= 49 * 16 * 64) return;
  int ci = idx & 63, t = idx >> 6;
  int co = t & 15, tap = t >> 4;
  float v = (co < 3) ? src[((size_t)co * 64 + ci) * 49 + tap] : 0.f;
  dst[idx] = (half_t)v;
}

// ---------------- conv0: reflect pad 3, 7x7, 3 -> 64, NHWC fp16 out ---------
__global__ __launch_bounds__(256) void conv0_kernel(
    const float* __restrict__ x, const float* __restrict__ w,
    const float* __restrict__ bias, half_t* __restrict__ out)
{
  const int H = 512, W = 512, CIN = 3;
  __shared__ float s_in[3][22][22];
  __shared__ float4 s_w[3 * 49][4];
  const int cog = blockIdx.x, tile = blockIdx.y, b = blockIdx.z;
  const int tx0 = (tile & 31) << 4, ty0 = (tile >> 5) << 4;
  const int tid = threadIdx.x, tx = tid & 15, ty = tid >> 4;

  for (int idx = tid; idx < CIN * 49 * 16; idx += 256) {
    int j = idx & 15, r = idx >> 4;
    ((float*)s_w)[r * 16 + j] = w[(cog * 16 + j) * (CIN * 49) + r];
  }
  for (int idx = tid; idx < CIN * 22 * 22; idx += 256) {
    int ci = idx / 484, rr = idx % 484;
    int iy = rr / 22, ix = rr % 22;
    int gy = ty0 + iy - 3, gx = tx0 + ix - 3;
    gy = gy < 0 ? -gy : (gy >= H ? 2 * H - 2 - gy : gy);
    gx = gx < 0 ? -gx : (gx >= W ? 2 * W - 2 - gx : gx);
    s_in[ci][iy][ix] = x[((size_t)(b * CIN + ci) * H + gy) * W + gx];
  }
  __syncthreads();

  float acc[16];
#pragma unroll
  for (int j = 0; j < 16; ++j) acc[j] = 0.f;

#pragma unroll
  for (int ci = 0; ci < 3; ++ci)
    for (int ky = 0; ky < 7; ++ky)
#pragma unroll
      for (int kx = 0; kx < 7; ++kx) {
        float v = s_in[ci][ty + ky][tx + kx];
        int r = (ci * 7 + ky) * 7 + kx;
#pragma unroll
        for (int q = 0; q < 4; ++q) {
          float4 wv = s_w[r][q];
          acc[q * 4 + 0] += v * wv.x;
          acc[q * 4 + 1] += v * wv.y;
          acc[q * 4 + 2] += v * wv.z;
          acc[q * 4 + 3] += v * wv.w;
        }
      }
  const int oy = ty0 + ty, ox = tx0 + tx;
  halfx8 o0, o1;
#pragma unroll
  for (int j = 0; j < 8; ++j) {
    o0[j] = (half_t)(acc[j] + bias[cog * 16 + j]);
    o1[j] = (half_t)(acc[8 + j] + bias[cog * 16 + 8 + j]);
  }
  size_t obase = ((size_t)(b * 512 + oy) * 512 + ox) * 64 + cog * 16;
  *(halfx8*)(&out[obase]) = o0;
  *(halfx8*)(&out[obase + 8]) = o1;
}

// ---------------- stats (NHWC): partial sums + atomics ----------------------
__global__ __launch_bounds__(256) void stats_part(
    const half_t* __restrict__ x, float* __restrict__ Ssum, int C, int S)
{
  const int b = blockIdx.y, tid = threadIdx.x;
  const size_t base = (size_t)b * S * C;
  const int E8 = (S * C) >> 3;
  float s[8], s2[8];
#pragma unroll
  for (int j = 0; j < 8; ++j) { s[j] = 0.f; s2[j] = 0.f; }
  for (int i8 = blockIdx.x * 256 + tid; i8 < E8; i8 += gridDim.x * 256) {
    halfx8 v = *(const halfx8*)(x + base + (size_t)i8 * 8);
#pragma unroll
    for (int j = 0; j < 8; ++j) {
      float f = (float)v[j];
      s[j] += f; s2[j] += f * f;
    }
  }
  __shared__ float part[256][16];
#pragma unroll
  for (int j = 0; j < 8; ++j) { part[tid][j] = s[j]; part[tid][8 + j] = s2[j]; }
  __syncthreads();
  const int T = C >> 3, reps = 256 / (C >> 3);
  for (int c = tid; c < C; c += 256) {
    int r = c >> 3, j = c & 7;
    float ss = 0.f, ss2 = 0.f;
    for (int m = 0; m < reps; ++m) {
      ss += part[r + m * T][j];
      ss2 += part[r + m * T][8 + j];
    }
    atomicAdd(&Ssum[(size_t)(b * C + c) * 2], ss);
    atomicAdd(&Ssum[(size_t)(b * C + c) * 2 + 1], ss2);
  }
}

__global__ __launch_bounds__(256) void finalize_stats(
    const float* __restrict__ Ssum, float* __restrict__ mean,
    float* __restrict__ rstd, int total, float invN)
{
  int idx = blockIdx.x * 256 + threadIdx.x;
  if (idx >= total) return;
  float sm = Ssum[(size_t)idx * 2], s2 = Ssum[(size_t)idx * 2 + 1];
  float m = sm * invN;
  float var = s2 * invN - m * m;
  mean[idx] = m;
  rstd[idx] = rsqrtf(var + 1e-5f);
}

// ---------------- down: 3x3 s2 conv, MFMA implicit GEMM ---------------------
__global__ __launch_bounds__(256) void down_mfma(
    const half_t* __restrict__ in, const half_t* __restrict__ wt,
    const float* __restrict__ bias, const float* __restrict__ mean,
    const float* __restrict__ rstd, half_t* __restrict__ out,
    int Cin, int Cout, int IH, int IW)
{
  const int OH = IH >> 1, OW = IW >> 1;
  __shared__ _Float16 sX[9 * 33 * 40];  // [y 9][x 33][ci 32 pad 40]
  const int tid = threadIdx.x;
  const int wave = tid >> 6, lane = tid & 63;
  const int ln = lane & 15, g = lane >> 4;
  const int cog = blockIdx.x, b = blockIdx.z;
  const int ntx = OW >> 4;
  const int ox0 = (blockIdx.y % ntx) << 4, oy0 = (blockIdx.y / ntx) << 2;
  const int iy0 = 2 * oy0 - 1, ix0 = 2 * ox0 - 1;
  const int coW = cog * 128 + wave * 32;
  const int q = tid & 3;

  floatx4 acc[4][2];
#pragma unroll
  for (int r = 0; r < 4; ++r)
#pragma unroll
    for (int n = 0; n < 2; ++n) acc[r][n] = floatx4{0.f, 0.f, 0.f, 0.f};

  for (int c0 = 0; c0 < Cin; c0 += 32) {
    float mq[8], rq[8];
#pragma unroll
    for (int j = 0; j < 8; ++j) {
      int cc = c0 + q * 8 + j;
      mq[j] = mean[b * Cin + cc];
      rq[j] = rstd[b * Cin + cc];
    }
    __syncthreads();
    for (int idx = tid; idx < 9 * 33 * 4; idx += 256) {
      int p = idx >> 2;
      int y = p / 33, xx = p % 33;
      int gy = iy0 + y, gx = ix0 + xx;
      halfx8 v = {0, 0, 0, 0, 0, 0, 0, 0};
      if ((unsigned)gy < (unsigned)IH && (unsigned)gx < (unsigned)IW) {
        v = *(const halfx8*)(in + ((size_t)(b * IH + gy) * IW + gx) * Cin + c0 + q * 8);
#pragma unroll
        for (int j = 0; j < 8; ++j) {
          float f = ((float)v[j] - mq[j]) * rq[j];
          v[j] = (_Float16)(f > 0.f ? f : 0.f);
        }
      }
      *(halfx8*)(&sX[(y * 33 + xx) * 40 + q * 8]) = v;
    }
    __syncthreads();
#pragma unroll
    for (int tap = 0; tap < 9; ++tap) {
      const int ky = tap / 3, kx = tap % 3;
      halfx8 wb0 = *(const halfx8*)(wt + ((size_t)tap * Cout + coW + ln) * Cin + c0 + g * 8);
      halfx8 wb1 = *(const halfx8*)(wt + ((size_t)tap * Cout + coW + 16 + ln) * Cin + c0 + g * 8);
#pragma unroll
      for (int r = 0; r < 4; ++r) {
        halfx8 a = *(const halfx8*)(&sX[((2 * r + ky) * 33 + 2 * ln + kx) * 40 + g * 8]);
        acc[r][0] = __builtin_amdgcn_mfma_f32_16x16x32_f16(a, wb0, acc[r][0], 0, 0, 0);
        acc[r][1] = __builtin_amdgcn_mfma_f32_16x16x32_f16(a, wb1, acc[r][1], 0, 0, 0);
      }
    }
  }
#pragma unroll
  for (int nt = 0; nt < 2; ++nt) {
    int co = coW + nt * 16 + ln;
    float bs = bias[co];
#pragma unroll
    for (int r = 0; r < 4; ++r)
#pragma unroll
      for (int i = 0; i < 4; ++i) {
        int oy = oy0 + r, ox = ox0 + g * 4 + i;
        out[((size_t)(b * OH + oy) * OW + ox) * Cout + co] = (half_t)(acc[r][nt][i] + bs);
      }
  }
}

// ---------------- up: convT k3 s2 p1 op1, MFMA via parity classes -----------
__global__ __launch_bounds__(256) void up_mfma(
    const half_t* __restrict__ in, const half_t* __restrict__ wt,
    const float* __restrict__ bias, const float* __restrict__ mean,
    const float* __restrict__ rstd, half_t* __restrict__ out,
    int Cin, int Cout, int IH, int IW)
{
  const int OH = IH << 1, OW = IW << 1;
  __shared__ _Float16 sX[5 * 17 * 40];  // [y 5][x 17][ci 32 pad 40]
  const int tid = threadIdx.x;
  const int wave = tid >> 6, lane = tid & 63;
  const int ln = lane & 15, g = lane >> 4;
  const int cog = blockIdx.x, b = blockIdx.z;
  const int ntx = OW >> 5;
  const int ox0 = (blockIdx.y % ntx) << 5, oy0 = (blockIdx.y / ntx) << 3;
  const int iyb = oy0 >> 1, ixb = ox0 >> 1;
  const int co = cog * 64 + wave * 16 + ln;
  const int q = tid & 3;

  floatx4 acc[4][4];  // [class][oyc]
#pragma unroll
  for (int c = 0; c < 4; ++c)
#pragma unroll
    for (int r = 0; r < 4; ++r) acc[c][r] = floatx4{0.f, 0.f, 0.f, 0.f};

  for (int c0 = 0; c0 < Cin; c0 += 32) {
    float mq[8], rq[8];
#pragma unroll
    for (int j = 0; j < 8; ++j) {
      int cc = c0 + q * 8 + j;
      mq[j] = mean[b * Cin + cc];
      rq[j] = rstd[b * Cin + cc];
    }
    __syncthreads();
    for (int idx = tid; idx < 5 * 17 * 4; idx += 256) {
      int p = idx >> 2;
      int y = p / 17, xx = p % 17;
      int gy = iyb + y, gx = ixb + xx;
      halfx8 v = {0, 0, 0, 0, 0, 0, 0, 0};
      if (gy < IH && gx < IW) {
        v = *(const halfx8*)(in + ((size_t)(b * IH + gy) * IW + gx) * Cin + c0 + q * 8);
#pragma unroll
        for (int j = 0; j < 8; ++j) {
          float f = ((float)v[j] - mq[j]) * rq[j];
          v[j] = (_Float16)(f > 0.f ? f : 0.f);
        }
      }
      *(halfx8*)(&sX[(y * 17 + xx) * 40 + q * 8]) = v;
    }
    __syncthreads();
#pragma unroll
    for (int tap = 0; tap < 9; ++tap) {
      const int ky = tap / 3, kx = tap % 3;
      const int cls = ((ky == 1) ? 0 : 2) + ((kx == 1) ? 0 : 1);
      const int dy = (ky == 0) ? 1 : 0;
      const int dx = (kx == 0) ? 1 : 0;
      halfx8 wb = *(const halfx8*)(wt + ((size_t)tap * Cout + co) * Cin + c0 + g * 8);
#pragma unroll
      for (int r = 0; r < 4; ++r) {
        halfx8 a = *(const halfx8*)(&sX[((r + dy) * 17 + ln + dx) * 40 + g * 8]);
        acc[cls][r] = __builtin_amdgcn_mfma_f32_16x16x32_f16(a, wb, acc[cls][r], 0, 0, 0);
      }
    }
  }
  float bs = bias[co];
#pragma unroll
  for (int cls = 0; cls < 4; ++cls) {
    const int ey = cls >> 1, ex = cls & 1;
#pragma unroll
    for (int r = 0; r < 4; ++r)
#pragma unroll
      for (int i = 0; i < 4; ++i) {
        int oy = oy0 + 2 * r + ey;
        int ox = ox0 + 2 * (g * 4 + i) + ex;
        out[((size_t)(b * OH + oy) * OW + ox) * Cout + co] = (half_t)(acc[cls][r][i] + bs);
      }
  }
}

// ---------------- final: reflect pad 3, 7x7, 64 -> 3(pad16), MFMA + tanh ----
// Block 256 = 4 waves; 16x16 output tile; full 64-ci halo staged once.
// GEMM: M=256 spatial (16 M-tiles), N=16 co (3 real), K=49 taps x 64 ci.
__global__ __launch_bounds__(256) void convf_mfma(
    const half_t* __restrict__ in, const half_t* __restrict__ wt,
    const float* __restrict__ bias, const float* __restrict__ mean,
    const float* __restrict__ rstd, float* __restrict__ out)
{
  const int H = 512, W = 512;
  __shared__ _Float16 sX[22 * 22 * 72];  // [pixel 484][ci 64 pad 72] = 69.7 KB
  const int tile = blockIdx.x, b = blockIdx.y;
  const int tx0 = (tile & 31) << 4, ty0 = (tile >> 5) << 4;
  const int tid = threadIdx.x;
  const int wave = tid >> 6, lane = tid & 63;
  const int ln = lane & 15, g = lane >> 4;
  const int oct = tid & 7;

  float mq[8], rq[8];
#pragma unroll
  for (int j = 0; j < 8; ++j) {
    mq[j] = mean[b * 64 + oct * 8 + j];
    rq[j] = rstd[b * 64 + oct * 8 + j];
  }
  // stage full halo tile, norm+relu fused (484 pixels x 8 ci-octets)
  for (int u = tid; u < 484 * 8; u += 256) {
    int p = u >> 3;                 // oct == tid & 7 (256 % 8 == 0)
    int iy = p / 22, ix = p % 22;
    int gy = ty0 + iy - 3, gx = tx0 + ix - 3;
    gy = gy < 0 ? -gy : (gy >= H ? 2 * H - 2 - gy : gy);
    gx = gx < 0 ? -gx : (gx >= W ? 2 * W - 2 - gx : gx);
    halfx8 v = *(const halfx8*)(in + ((size_t)(b * H + gy) * W + gx) * 64 + oct * 8);
#pragma unroll
    for (int j = 0; j < 8; ++j) {
      float f = ((float)v[j] - mq[j]) * rq[j];
      v[j] = (_Float16)(f > 0.f ? f : 0.f);
    }
    *(halfx8*)(&sX[p * 72 + oct * 8]) = v;
  }
  __syncthreads();

  floatx4 acc[4];  // 4 M-tiles (output rows) per wave
#pragma unroll
  for (int r = 0; r < 4; ++r) acc[r] = floatx4{0.f, 0.f, 0.f, 0.f};

  for (int tap = 0; tap < 49; ++tap) {
    const int ky = tap / 7, kx = tap % 7;
#pragma unroll
    for (int kc = 0; kc < 2; ++kc) {
      halfx8 wb = *(const halfx8*)(wt + ((size_t)tap * 16 + ln) * 64 + kc * 32 + g * 8);
#pragma unroll
      for (int rr = 0; rr < 4; ++rr) {
        int y = wave * 4 + rr;  // output row within tile
        halfx8 a = *(const halfx8*)(&sX[((y + ky) * 22 + ln + kx) * 72 + kc * 32 + g * 8]);
        acc[rr] = __builtin_amdgcn_mfma_f32_16x16x32_f16(a, wb, acc[rr], 0, 0, 0);
      }
    }
  }
  // D: col=ln -> co, row=g*4+i -> x
  if (ln < 3) {
    float bs = bias[ln];
#pragma unroll
    for (int rr = 0; rr < 4; ++rr) {
      int oy = ty0 + wave * 4 + rr;
#pragma unroll
      for (int i = 0; i < 4; ++i) {
        int ox = tx0 + g * 4 + i;
        out[((size_t)(b * 3 + ln) * H + oy) * W + ox] = tanhf(acc[rr][i] + bs);
      }
    }
  }
}

// ---------------- masked pooling --------------------------------------------
__global__ __launch_bounds__(256) void pool_sum_kernel(
    const float* __restrict__ f, const int* __restrict__ inst,
    float* __restrict__ P)
{
  const int N = 512 * 512;
  const int b = blockIdx.x, chunk = blockIdx.y;
  const int per = N / 32;
  const int base = chunk * per;
  float s0 = 0.f, s1 = 0.f, s2 = 0.f, c = 0.f;
  for (int i = base + threadIdx.x; i < base + per; i += 256) {
    if (inst[b * N + i] == 1) {
      c += 1.f;
      s0 += f[(size_t)(b * 3 + 0) * N + i];
      s1 += f[(size_t)(b * 3 + 1) * N + i];
      s2 += f[(size_t)(b * 3 + 2) * N + i];
    }
  }
#pragma unroll
  for (int off = 32; off > 0; off >>= 1) {
    s0 += __shfl_down(s0, off); s1 += __shfl_down(s1, off);
    s2 += __shfl_down(s2, off); c += __shfl_down(c, off);
  }
  __shared__ float red[4][4];
  int wv = threadIdx.x >> 6;
  if ((threadIdx.x & 63) == 0) {
    red[wv][0] = s0; red[wv][1] = s1; red[wv][2] = s2; red[wv][3] = c;
  }
  __syncthreads();
  if (threadIdx.x == 0) {
    float t0 = red[0][0] + red[1][0] + red[2][0] + red[3][0];
    float t1 = red[0][1] + red[1][1] + red[2][1] + red[3][1];
    float t2 = red[0][2] + red[1][2] + red[2][2] + red[3][2];
    float tc = red[0][3] + red[1][3] + red[2][3] + red[3][3];
    atomicAdd(&P[b * 4 + 0], t0);
    atomicAdd(&P[b * 4 + 1], t1);
    atomicAdd(&P[b * 4 + 2], t2);
    atomicAdd(&P[b * 4 + 3], tc);
  }
}

__global__ __launch_bounds__(256) void pool_scatter_kernel(
    const int* __restrict__ inst, const float* __restrict__ P,
    float* __restrict__ out)
{
  const int N = 512 * 512;
  int idx = blockIdx.x * 256 + threadIdx.x;
  if (idx >= 4 * N) return;
  int b = idx >> 18;
  int i = idx & (N - 1);
  bool m = inst[idx] == 1;
  float inv = 1.f / P[b * 4 + 3];
  out[(size_t)(b * 3 + 0) * N + i] = m ? P[b * 4 + 0] * inv : 0.f;
  out[(size_t)(b * 3 + 1) * N + i] = m ? P[b * 4 + 1] * inv : 0.f;
  out[(size_t)(b * 3 + 2) * N + i] = m ? P[b * 4 + 2] * inv : 0.f;
}

// ---------------------------------------------------------------------------
extern "C" void kernel_launch(void* const* d_in, const int* in_sizes, int n_in,
                              void* d_out, int out_size, void* d_ws, size_t ws_size,
                              hipStream_t stream)
{
  (void)in_sizes; (void)n_in; (void)out_size; (void)ws_size;
  const float* x    = (const float*)d_in[0];
  const int*   inst = (const int*)d_in[1];
  const float* w0   = (const float*)d_in[2];
  const float* b0   = (const float*)d_in[3];
  const float *dw[4], *db[4], *uw[4], *ub[4];
  for (int i = 0; i < 4; ++i) {
    dw[i] = (const float*)d_in[4 + 2 * i];
    db[i] = (const float*)d_in[5 + 2 * i];
    uw[i] = (const float*)d_in[12 + 2 * i];
    ub[i] = (const float*)d_in[13 + 2 * i];
  }
  const float* wf = (const float*)d_in[20];
  const float* bf = (const float*)d_in[21];

  // ---- workspace layout (total ~201.8 MB) ----
  char* base = (char*)d_ws;
  half_t* A  = (half_t*)base;
  half_t* Bh = (half_t*)(base + 134217728);
  float*  F  = (float*)(base + 134217728);            // aliases B after u3
  float*  Ssum   = (float*)(base + 201326592);
  float*  S_mean = (float*)(base + 201326592 + 32768);
  float*  S_rstd = (float*)(base + 201326592 + 49152);
  float*  P      = (float*)(base + 201326592 + 65536);
  half_t* WTp0   = (half_t*)(base + 201326592 + 66560);
  half_t* WTp1   = (half_t*)(base + 201326592 + 66560 + 147456);
  half_t* WTf    = (half_t*)(base + 201326592 + 66560 + 294912);  // 100,352 B
  half_t* WTA    = (half_t*)(base + 124780544);   // A-tail (dead-region reuse)
  half_t* WTB    = (half_t*)(base + 191889408);   // B-tail

  auto XFORM = [&](const float* src, half_t* dst, int Ci, int Co, int mode) {
    int tot = Ci * Co * 9;
    transform_w<<<dim3((tot + 255) / 256), 256, 0, stream>>>(src, dst, Ci, Co, mode);
  };
  auto STATS = [&](const half_t* p, int C, int S) {
    hipMemsetAsync(Ssum, 0, 4096 * 2 * sizeof(float), stream);
    stats_part<<<dim3(128, 4), 256, 0, stream>>>(p, Ssum, C, S);
    finalize_stats<<<dim3((4 * C + 255) / 256), 256, 0, stream>>>(
        Ssum, S_mean, S_rstd, 4 * C, 1.f / (float)S);
  };

  // conv0 -> A (raw); stats
  conv0_kernel<<<dim3(4, 1024, 4), 256, 0, stream>>>(x, w0, b0, A);
  transform_wf<<<dim3((49 * 16 * 64 + 255) / 256), 256, 0, stream>>>(wf, WTf);
  STATS(A, 64, 512 * 512);

  // d0: A(64,512) -> B(128,256)
  XFORM(dw[0], WTp0, 64, 128, 0);
  down_mfma<<<dim3(1, 1024, 4), 256, 0, stream>>>(A, WTp0, db[0], S_mean, S_rstd, Bh, 64, 128, 512, 512);
  STATS(Bh, 128, 256 * 256);
  // d1: B -> A(256,128)
  XFORM(dw[1], WTA, 128, 256, 0);
  down_mfma<<<dim3(2, 256, 4), 256, 0, stream>>>(Bh, WTA, db[1], S_mean, S_rstd, A, 128, 256, 256, 256);
  STATS(A, 256, 128 * 128);
  // d2: A -> B(512,64)
  XFORM(dw[2], WTB, 256, 512, 0);
  down_mfma<<<dim3(4, 64, 4), 256, 0, stream>>>(A, WTB, db[2], S_mean, S_rstd, Bh, 256, 512, 128, 128);
  STATS(Bh, 512, 64 * 64);
  // d3: B -> A(1024,32)
  XFORM(dw[3], WTA, 512, 1024, 0);
  down_mfma<<<dim3(8, 16, 4), 256, 0, stream>>>(Bh, WTA, db[3], S_mean, S_rstd, A, 512, 1024, 64, 64);
  STATS(A, 1024, 32 * 32);

  // u0: A(1024,32) -> B(512,64)
  XFORM(uw[0], WTB, 1024, 512, 1);
  up_mfma<<<dim3(8, 16, 4), 256, 0, stream>>>(A, WTB, ub[0], S_mean, S_rstd, Bh, 1024, 512, 32, 32);
  STATS(Bh, 512, 64 * 64);
  // u1: B -> A(256,128)
  XFORM(uw[1], WTA, 512, 256, 1);
  up_mfma<<<dim3(4, 64, 4), 256, 0, stream>>>(Bh, WTA, ub[1], S_mean, S_rstd, A, 512, 256, 64, 64);
  STATS(A, 256, 128 * 128);
  // u2: A -> B(128,256)
  XFORM(uw[2], WTA, 256, 128, 1);
  up_mfma<<<dim3(2, 256, 4), 256, 0, stream>>>(A, WTA, ub[2], S_mean, S_rstd, Bh, 256, 128, 128, 128);
  STATS(Bh, 128, 256 * 256);
  // u3: B -> A(64,512)
  XFORM(uw[3], WTp1, 128, 64, 1);
  up_mfma<<<dim3(1, 1024, 4), 256, 0, stream>>>(Bh, WTp1, ub[3], S_mean, S_rstd, A, 128, 64, 256, 256);
  STATS(A, 64, 512 * 512);

  // final conv (MFMA) -> F (fp32 CHW), then pooling
  convf_mfma<<<dim3(1024, 4), 256, 0, stream>>>(A, WTf, bf, S_mean, S_rstd, F);
  hipMemsetAsync(P, 0, 16 * sizeof(float), stream);
  pool_sum_kernel<<<dim3(4, 32), 256, 0, stream>>>(F, inst, P);
  pool_scatter_kernel<<<dim3(4096), 256, 0, stream>>>(inst, P, (float*)d_out);
}

// Round 6
// 1590.716 us; speedup vs baseline: 7.9115x; 1.1667x over previous
//
#include <hip/hip_runtime.h>
#include <math.h>

// ---------------------------------------------------------------------------
// Encoder on MI355X.
// NHWC fp16 activations; ALL convs (7x7 first/last, 3x3 down/up) as tap-wise
// implicit GEMM on mfma_f32_16x16x32_f16 (fp32 accum). InstanceNorm+ReLU
// fused into staging. Weights pre-cast to fp16 [tap][co][ci] into dead
// workspace regions each launch.
// ---------------------------------------------------------------------------

typedef _Float16 half_t;
typedef _Float16 halfx8 __attribute__((ext_vector_type(8)));
typedef _Float16 halfx4 __attribute__((ext_vector_type(4)));
typedef float floatx4 __attribute__((ext_vector_type(4)));

static __device__ __forceinline__ float xform(float v, float m, float r) {
  v = (v - m) * r;
  return v > 0.f ? v : 0.f;
}

// ---------------- weight transform: -> fp16 [tap][Cout][Cin] ----------------
// mode 0: src OIHW [Cout][Cin][3][3]; mode 1: src IOHW [Cin][Cout][3][3]
__global__ __launch_bounds__(256) void transform_w(
    const float* __restrict__ src, half_t* __restrict__ dst,
    int Cin, int Cout, int mode)
{
  int idx = blockIdx.x * 256 + threadIdx.x;
  int total = Cin * Cout * 9;
  if (idx >= total) return;
  int tap = idx % 9, t2 = idx / 9;
  int co, ci;
  if (mode == 0) { ci = t2 % Cin; co = t2 / Cin; }
  else           { co = t2 % Cout; ci = t2 / Cout; }
  dst[((size_t)tap * Cout + co) * Cin + ci] = (half_t)src[idx];
}

// final-conv weights: src [3][64][7][7] -> dst [tap49][co16(pad0)][ci64]
__global__ __launch_bounds__(256) void transform_wf(
    const float* __restrict__ src, half_t* __restrict__ dst)
{
  int idx = blockIdx.x * 256 + threadIdx.x;
  if (idx >= 49 * 16 * 64) return;
  int ci = idx & 63, t = idx >> 6;
  int co = t & 15, tap = t >> 4;
  float v = (co < 3) ? src[((size_t)co * 64 + ci) * 49 + tap] : 0.f;
  dst[idx] = (half_t)v;
}

// first-conv weights: src [64][3][7][7] -> dst [ky7][co64][k32], k=kx*4+ci
__global__ __launch_bounds__(256) void transform_w0(
    const float* __restrict__ src, half_t* __restrict__ dst)
{
  int idx = blockIdx.x * 256 + threadIdx.x;
  if (idx >= 7 * 64 * 32) return;
  int k = idx & 31, t = idx >> 5;
  int co = t & 63, ky = t >> 6;
  int kx = k >> 2, ci = k & 3;
  float v = (ci < 3 && kx < 7) ? src[(((size_t)co * 3 + ci) * 7 + ky) * 7 + kx] : 0.f;
  dst[idx] = (half_t)v;
}

// ---------------- conv0: reflect pad 3, 7x7, 3 -> 64, MFMA ------------------
// K = kx(7, pad8) x ci(3, pad4) per ky row; M=256 spatial, N=64 co.
__global__ __launch_bounds__(256) void conv0_mfma(
    const float* __restrict__ x, const half_t* __restrict__ wt,
    const float* __restrict__ bias, half_t* __restrict__ out)
{
  const int H = 512, W = 512;
  __shared__ _Float16 sX[22 * 24 * 4];   // [row 22][col 24][ci 4]  (4.2 KB)
  __shared__ _Float16 sO[256 * 72];      // [pixel 256][co 64 pad 72] (36.9 KB)
  const int tile = blockIdx.x, b = blockIdx.y;
  const int tx0 = (tile & 31) << 4, ty0 = (tile >> 5) << 4;
  const int tid = threadIdx.x;
  const int wave = tid >> 6, lane = tid & 63;
  const int ln = lane & 15, g = lane >> 4;

  // stage input (reflect pad); cols 22/23 and ci=3 are zeros
  for (int u = tid; u < 22 * 24; u += 256) {
    int row = u / 24, col = u % 24;
    halfx4 v = {0, 0, 0, 0};
    if (col < 22) {
      int gy = ty0 + row - 3, gx = tx0 + col - 3;
      gy = gy < 0 ? -gy : (gy >= H ? 2 * H - 2 - gy : gy);
      gx = gx < 0 ? -gx : (gx >= W ? 2 * W - 2 - gx : gx);
      size_t p = (size_t)b * 3 * H * W + (size_t)gy * W + gx;
      v[0] = (_Float16)x[p];
      v[1] = (_Float16)x[p + H * W];
      v[2] = (_Float16)x[p + 2 * H * W];
    }
    *(halfx4*)(&sX[u * 4]) = v;
  }
  __syncthreads();

  floatx4 acc[4][4];  // [rr: row within wave-quarter][nt: co 16-group]
#pragma unroll
  for (int r = 0; r < 4; ++r)
#pragma unroll
    for (int n = 0; n < 4; ++n) acc[r][n] = floatx4{0.f, 0.f, 0.f, 0.f};

#pragma unroll
  for (int ky = 0; ky < 7; ++ky) {
    halfx8 wb[4];
#pragma unroll
    for (int nt = 0; nt < 4; ++nt)
      wb[nt] = *(const halfx8*)(wt + ((size_t)ky * 64 + nt * 16 + ln) * 32 + g * 8);
#pragma unroll
    for (int rr = 0; rr < 4; ++rr) {
      int y = wave * 4 + rr;
      halfx8 a = *(const halfx8*)(&sX[((y + ky) * 24 + ln + 2 * g) * 4]);
#pragma unroll
      for (int nt = 0; nt < 4; ++nt)
        acc[rr][nt] = __builtin_amdgcn_mfma_f32_16x16x32_f16(a, wb[nt], acc[rr][nt], 0, 0, 0);
    }
  }

  // epilogue: bias, transpose via LDS, vectorized NHWC store
  float bs[4];
#pragma unroll
  for (int nt = 0; nt < 4; ++nt) bs[nt] = bias[nt * 16 + ln];
#pragma unroll
  for (int rr = 0; rr < 4; ++rr)
#pragma unroll
    for (int nt = 0; nt < 4; ++nt)
#pragma unroll
      for (int i = 0; i < 4; ++i) {
        int p = (wave * 4 + rr) * 16 + g * 4 + i;
        sO[p * 72 + nt * 16 + ln] = (half_t)(acc[rr][nt][i] + bs[nt]);
      }
  __syncthreads();
  {
    int p = tid;
    int oy = ty0 + (p >> 4), ox = tx0 + (p & 15);
    size_t ob = ((size_t)(b * 512 + oy) * 512 + ox) * 64;
#pragma unroll
    for (int j = 0; j < 8; ++j)
      *(halfx8*)(&out[ob + j * 8]) = *(const halfx8*)(&sO[p * 72 + j * 8]);
  }
}

// ---------------- stats (NHWC): partial sums + atomics ----------------------
__global__ __launch_bounds__(256) void stats_part(
    const half_t* __restrict__ x, float* __restrict__ Ssum, int C, int S)
{
  const int b = blockIdx.y, tid = threadIdx.x;
  const size_t base = (size_t)b * S * C;
  const int E8 = (S * C) >> 3;
  float s[8], s2[8];
#pragma unroll
  for (int j = 0; j < 8; ++j) { s[j] = 0.f; s2[j] = 0.f; }
  for (int i8 = blockIdx.x * 256 + tid; i8 < E8; i8 += gridDim.x * 256) {
    halfx8 v = *(const halfx8*)(x + base + (size_t)i8 * 8);
#pragma unroll
    for (int j = 0; j < 8; ++j) {
      float f = (float)v[j];
      s[j] += f; s2[j] += f * f;
    }
  }
  __shared__ float part[256][16];
#pragma unroll
  for (int j = 0; j < 8; ++j) { part[tid][j] = s[j]; part[tid][8 + j] = s2[j]; }
  __syncthreads();
  const int T = C >> 3, reps = 256 / (C >> 3);
  for (int c = tid; c < C; c += 256) {
    int r = c >> 3, j = c & 7;
    float ss = 0.f, ss2 = 0.f;
    for (int m = 0; m < reps; ++m) {
      ss += part[r + m * T][j];
      ss2 += part[r + m * T][8 + j];
    }
    atomicAdd(&Ssum[(size_t)(b * C + c) * 2], ss);
    atomicAdd(&Ssum[(size_t)(b * C + c) * 2 + 1], ss2);
  }
}

__global__ __launch_bounds__(256) void finalize_stats(
    const float* __restrict__ Ssum, float* __restrict__ mean,
    float* __restrict__ rstd, int total, float invN)
{
  int idx = blockIdx.x * 256 + threadIdx.x;
  if (idx >= total) return;
  float sm = Ssum[(size_t)idx * 2], s2 = Ssum[(size_t)idx * 2 + 1];
  float m = sm * invN;
  float var = s2 * invN - m * m;
  mean[idx] = m;
  rstd[idx] = rsqrtf(var + 1e-5f);
}

// ---------------- down: 3x3 s2 conv, MFMA implicit GEMM ---------------------
__global__ __launch_bounds__(256) void down_mfma(
    const half_t* __restrict__ in, const half_t* __restrict__ wt,
    const float* __restrict__ bias, const float* __restrict__ mean,
    const float* __restrict__ rstd, half_t* __restrict__ out,
    int Cin, int Cout, int IH, int IW)
{
  const int OH = IH >> 1, OW = IW >> 1;
  __shared__ _Float16 sX[9 * 33 * 40];  // [y 9][x 33][ci 32 pad 40]
  const int tid = threadIdx.x;
  const int wave = tid >> 6, lane = tid & 63;
  const int ln = lane & 15, g = lane >> 4;
  const int cog = blockIdx.x, b = blockIdx.z;
  const int ntx = OW >> 4;
  const int ox0 = (blockIdx.y % ntx) << 4, oy0 = (blockIdx.y / ntx) << 2;
  const int iy0 = 2 * oy0 - 1, ix0 = 2 * ox0 - 1;
  const int coW = cog * 128 + wave * 32;
  const int q = tid & 3;

  floatx4 acc[4][2];
#pragma unroll
  for (int r = 0; r < 4; ++r)
#pragma unroll
    for (int n = 0; n < 2; ++n) acc[r][n] = floatx4{0.f, 0.f, 0.f, 0.f};

  for (int c0 = 0; c0 < Cin; c0 += 32) {
    float mq[8], rq[8];
#pragma unroll
    for (int j = 0; j < 8; ++j) {
      int cc = c0 + q * 8 + j;
      mq[j] = mean[b * Cin + cc];
      rq[j] = rstd[b * Cin + cc];
    }
    __syncthreads();
    for (int idx = tid; idx < 9 * 33 * 4; idx += 256) {
      int p = idx >> 2;
      int y = p / 33, xx = p % 33;
      int gy = iy0 + y, gx = ix0 + xx;
      halfx8 v = {0, 0, 0, 0, 0, 0, 0, 0};
      if ((unsigned)gy < (unsigned)IH && (unsigned)gx < (unsigned)IW) {
        v = *(const halfx8*)(in + ((size_t)(b * IH + gy) * IW + gx) * Cin + c0 + q * 8);
#pragma unroll
        for (int j = 0; j < 8; ++j) {
          float f = ((float)v[j] - mq[j]) * rq[j];
          v[j] = (_Float16)(f > 0.f ? f : 0.f);
        }
      }
      *(halfx8*)(&sX[(y * 33 + xx) * 40 + q * 8]) = v;
    }
    __syncthreads();
#pragma unroll
    for (int tap = 0; tap < 9; ++tap) {
      const int ky = tap / 3, kx = tap % 3;
      halfx8 wb0 = *(const halfx8*)(wt + ((size_t)tap * Cout + coW + ln) * Cin + c0 + g * 8);
      halfx8 wb1 = *(const halfx8*)(wt + ((size_t)tap * Cout + coW + 16 + ln) * Cin + c0 + g * 8);
#pragma unroll
      for (int r = 0; r < 4; ++r) {
        halfx8 a = *(const halfx8*)(&sX[((2 * r + ky) * 33 + 2 * ln + kx) * 40 + g * 8]);
        acc[r][0] = __builtin_amdgcn_mfma_f32_16x16x32_f16(a, wb0, acc[r][0], 0, 0, 0);
        acc[r][1] = __builtin_amdgcn_mfma_f32_16x16x32_f16(a, wb1, acc[r][1], 0, 0, 0);
      }
    }
  }
#pragma unroll
  for (int nt = 0; nt < 2; ++nt) {
    int co = coW + nt * 16 + ln;
    float bs = bias[co];
#pragma unroll
    for (int r = 0; r < 4; ++r)
#pragma unroll
      for (int i = 0; i < 4; ++i) {
        int oy = oy0 + r, ox = ox0 + g * 4 + i;
        out[((size_t)(b * OH + oy) * OW + ox) * Cout + co] = (half_t)(acc[r][nt][i] + bs);
      }
  }
}

// ---------------- up: convT k3 s2 p1 op1, MFMA via parity classes -----------
__global__ __launch_bounds__(256) void up_mfma(
    const half_t* __restrict__ in, const half_t* __restrict__ wt,
    const float* __restrict__ bias, const float* __restrict__ mean,
    const float* __restrict__ rstd, half_t* __restrict__ out,
    int Cin, int Cout, int IH, int IW)
{
  const int OH = IH << 1, OW = IW << 1;
  __shared__ _Float16 sX[5 * 17 * 40];  // [y 5][x 17][ci 32 pad 40]
  const int tid = threadIdx.x;
  const int wave = tid >> 6, lane = tid & 63;
  const int ln = lane & 15, g = lane >> 4;
  const int cog = blockIdx.x, b = blockIdx.z;
  const int ntx = OW >> 5;
  const int ox0 = (blockIdx.y % ntx) << 5, oy0 = (blockIdx.y / ntx) << 3;
  const int iyb = oy0 >> 1, ixb = ox0 >> 1;
  const int co = cog * 64 + wave * 16 + ln;
  const int q = tid & 3;

  floatx4 acc[4][4];  // [class][oyc]
#pragma unroll
  for (int c = 0; c < 4; ++c)
#pragma unroll
    for (int r = 0; r < 4; ++r) acc[c][r] = floatx4{0.f, 0.f, 0.f, 0.f};

  for (int c0 = 0; c0 < Cin; c0 += 32) {
    float mq[8], rq[8];
#pragma unroll
    for (int j = 0; j < 8; ++j) {
      int cc = c0 + q * 8 + j;
      mq[j] = mean[b * Cin + cc];
      rq[j] = rstd[b * Cin + cc];
    }
    __syncthreads();
    for (int idx = tid; idx < 5 * 17 * 4; idx += 256) {
      int p = idx >> 2;
      int y = p / 17, xx = p % 17;
      int gy = iyb + y, gx = ixb + xx;
      halfx8 v = {0, 0, 0, 0, 0, 0, 0, 0};
      if (gy < IH && gx < IW) {
        v = *(const halfx8*)(in + ((size_t)(b * IH + gy) * IW + gx) * Cin + c0 + q * 8);
#pragma unroll
        for (int j = 0; j < 8; ++j) {
          float f = ((float)v[j] - mq[j]) * rq[j];
          v[j] = (_Float16)(f > 0.f ? f : 0.f);
        }
      }
      *(halfx8*)(&sX[(y * 17 + xx) * 40 + q * 8]) = v;
    }
    __syncthreads();
#pragma unroll
    for (int tap = 0; tap < 9; ++tap) {
      const int ky = tap / 3, kx = tap % 3;
      const int cls = ((ky == 1) ? 0 : 2) + ((kx == 1) ? 0 : 1);
      const int dy = (ky == 0) ? 1 : 0;
      const int dx = (kx == 0) ? 1 : 0;
      halfx8 wb = *(const halfx8*)(wt + ((size_t)tap * Cout + co) * Cin + c0 + g * 8);
#pragma unroll
      for (int r = 0; r < 4; ++r) {
        halfx8 a = *(const halfx8*)(&sX[((r + dy) * 17 + ln + dx) * 40 + g * 8]);
        acc[cls][r] = __builtin_amdgcn_mfma_f32_16x16x32_f16(a, wb, acc[cls][r], 0, 0, 0);
      }
    }
  }
  float bs = bias[co];
#pragma unroll
  for (int cls = 0; cls < 4; ++cls) {
    const int ey = cls >> 1, ex = cls & 1;
#pragma unroll
    for (int r = 0; r < 4; ++r)
#pragma unroll
      for (int i = 0; i < 4; ++i) {
        int oy = oy0 + 2 * r + ey;
        int ox = ox0 + 2 * (g * 4 + i) + ex;
        out[((size_t)(b * OH + oy) * OW + ox) * Cout + co] = (half_t)(acc[cls][r][i] + bs);
      }
  }
}

// ---------------- final: reflect pad 3, 7x7, 64 -> 3(pad16), MFMA + tanh ----
__global__ __launch_bounds__(256) void convf_mfma(
    const half_t* __restrict__ in, const half_t* __restrict__ wt,
    const float* __restrict__ bias, const float* __restrict__ mean,
    const float* __restrict__ rstd, float* __restrict__ out)
{
  const int H = 512, W = 512;
  __shared__ _Float16 sX[22 * 22 * 72];  // [pixel 484][ci 64 pad 72] = 69.7 KB
  const int tile = blockIdx.x, b = blockIdx.y;
  const int tx0 = (tile & 31) << 4, ty0 = (tile >> 5) << 4;
  const int tid = threadIdx.x;
  const int wave = tid >> 6, lane = tid & 63;
  const int ln = lane & 15, g = lane >> 4;
  const int oct = tid & 7;

  float mq[8], rq[8];
#pragma unroll
  for (int j = 0; j < 8; ++j) {
    mq[j] = mean[b * 64 + oct * 8 + j];
    rq[j] = rstd[b * 64 + oct * 8 + j];
  }
  for (int u = tid; u < 484 * 8; u += 256) {
    int p = u >> 3;
    int iy = p / 22, ix = p % 22;
    int gy = ty0 + iy - 3, gx = tx0 + ix - 3;
    gy = gy < 0 ? -gy : (gy >= H ? 2 * H - 2 - gy : gy);
    gx = gx < 0 ? -gx : (gx >= W ? 2 * W - 2 - gx : gx);
    halfx8 v = *(const halfx8*)(in + ((size_t)(b * H + gy) * W + gx) * 64 + oct * 8);
#pragma unroll
    for (int j = 0; j < 8; ++j) {
      float f = ((float)v[j] - mq[j]) * rq[j];
      v[j] = (_Float16)(f > 0.f ? f : 0.f);
    }
    *(halfx8*)(&sX[p * 72 + oct * 8]) = v;
  }
  __syncthreads();

  floatx4 acc[4];
#pragma unroll
  for (int r = 0; r < 4; ++r) acc[r] = floatx4{0.f, 0.f, 0.f, 0.f};

  for (int tap = 0; tap < 49; ++tap) {
    const int ky = tap / 7, kx = tap % 7;
#pragma unroll
    for (int kc = 0; kc < 2; ++kc) {
      halfx8 wb = *(const halfx8*)(wt + ((size_t)tap * 16 + ln) * 64 + kc * 32 + g * 8);
#pragma unroll
      for (int rr = 0; rr < 4; ++rr) {
        int y = wave * 4 + rr;
        halfx8 a = *(const halfx8*)(&sX[((y + ky) * 22 + ln + kx) * 72 + kc * 32 + g * 8]);
        acc[rr] = __builtin_amdgcn_mfma_f32_16x16x32_f16(a, wb, acc[rr], 0, 0, 0);
      }
    }
  }
  if (ln < 3) {
    float bs = bias[ln];
#pragma unroll
    for (int rr = 0; rr < 4; ++rr) {
      int oy = ty0 + wave * 4 + rr;
#pragma unroll
      for (int i = 0; i < 4; ++i) {
        int ox = tx0 + g * 4 + i;
        out[((size_t)(b * 3 + ln) * H + oy) * W + ox] = tanhf(acc[rr][i] + bs);
      }
    }
  }
}

// ---------------- masked pooling --------------------------------------------
__global__ __launch_bounds__(256) void pool_sum_kernel(
    const float* __restrict__ f, const int* __restrict__ inst,
    float* __restrict__ P)
{
  const int N = 512 * 512;
  const int b = blockIdx.x, chunk = blockIdx.y;
  const int per = N / 32;
  const int base = chunk * per;
  float s0 = 0.f, s1 = 0.f, s2 = 0.f, c = 0.f;
  for (int i = base + threadIdx.x; i < base + per; i += 256) {
    if (inst[b * N + i] == 1) {
      c += 1.f;
      s0 += f[(size_t)(b * 3 + 0) * N + i];
      s1 += f[(size_t)(b * 3 + 1) * N + i];
      s2 += f[(size_t)(b * 3 + 2) * N + i];
    }
  }
#pragma unroll
  for (int off = 32; off > 0; off >>= 1) {
    s0 += __shfl_down(s0, off); s1 += __shfl_down(s1, off);
    s2 += __shfl_down(s2, off); c += __shfl_down(c, off);
  }
  __shared__ float red[4][4];
  int wv = threadIdx.x >> 6;
  if ((threadIdx.x & 63) == 0) {
    red[wv][0] = s0; red[wv][1] = s1; red[wv][2] = s2; red[wv][3] = c;
  }
  __syncthreads();
  if (threadIdx.x == 0) {
    float t0 = red[0][0] + red[1][0] + red[2][0] + red[3][0];
    float t1 = red[0][1] + red[1][1] + red[2][1] + red[3][1];
    float t2 = red[0][2] + red[1][2] + red[2][2] + red[3][2];
    float tc = red[0][3] + red[1][3] + red[2][3] + red[3][3];
    atomicAdd(&P[b * 4 + 0], t0);
    atomicAdd(&P[b * 4 + 1], t1);
    atomicAdd(&P[b * 4 + 2], t2);
    atomicAdd(&P[b * 4 + 3], tc);
  }
}

__global__ __launch_bounds__(256) void pool_scatter_kernel(
    const int* __restrict__ inst, const float* __restrict__ P,
    float* __restrict__ out)
{
  const int N = 512 * 512;
  int idx = blockIdx.x * 256 + threadIdx.x;
  if (idx >= 4 * N) return;
  int b = idx >> 18;
  int i = idx & (N - 1);
  bool m = inst[idx] == 1;
  float inv = 1.f / P[b * 4 + 3];
  out[(size_t)(b * 3 + 0) * N + i] = m ? P[b * 4 + 0] * inv : 0.f;
  out[(size_t)(b * 3 + 1) * N + i] = m ? P[b * 4 + 1] * inv : 0.f;
  out[(size_t)(b * 3 + 2) * N + i] = m ? P[b * 4 + 2] * inv : 0.f;
}

// ---------------------------------------------------------------------------
extern "C" void kernel_launch(void* const* d_in, const int* in_sizes, int n_in,
                              void* d_out, int out_size, void* d_ws, size_t ws_size,
                              hipStream_t stream)
{
  (void)in_sizes; (void)n_in; (void)out_size; (void)ws_size;
  const float* x    = (const float*)d_in[0];
  const int*   inst = (const int*)d_in[1];
  const float* w0   = (const float*)d_in[2];
  const float* b0   = (const float*)d_in[3];
  const float *dw[4], *db[4], *uw[4], *ub[4];
  for (int i = 0; i < 4; ++i) {
    dw[i] = (const float*)d_in[4 + 2 * i];
    db[i] = (const float*)d_in[5 + 2 * i];
    uw[i] = (const float*)d_in[12 + 2 * i];
    ub[i] = (const float*)d_in[13 + 2 * i];
  }
  const float* wf = (const float*)d_in[20];
  const float* bf = (const float*)d_in[21];

  // ---- workspace layout (total ~201.8 MB) ----
  char* base = (char*)d_ws;
  half_t* A  = (half_t*)base;
  half_t* Bh = (half_t*)(base + 134217728);
  float*  F  = (float*)(base + 134217728);            // aliases B after u3
  float*  Ssum   = (float*)(base + 201326592);
  float*  S_mean = (float*)(base + 201326592 + 32768);
  float*  S_rstd = (float*)(base + 201326592 + 49152);
  float*  P      = (float*)(base + 201326592 + 65536);
  half_t* WTp0   = (half_t*)(base + 201326592 + 66560);
  half_t* WTp1   = (half_t*)(base + 201326592 + 66560 + 147456);
  half_t* WTf    = (half_t*)(base + 201326592 + 66560 + 294912);  // 100,352 B
  half_t* WT0    = (half_t*)(base + 201326592 + 66560 + 294912 + 100352); // 28,672 B
  half_t* WTA    = (half_t*)(base + 124780544);   // A-tail (dead-region reuse)
  half_t* WTB    = (half_t*)(base + 191889408);   // B-tail

  auto XFORM = [&](const float* src, half_t* dst, int Ci, int Co, int mode) {
    int tot = Ci * Co * 9;
    transform_w<<<dim3((tot + 255) / 256), 256, 0, stream>>>(src, dst, Ci, Co, mode);
  };
  auto STATS = [&](const half_t* p, int C, int S) {
    hipMemsetAsync(Ssum, 0, 4096 * 2 * sizeof(float), stream);
    stats_part<<<dim3(128, 4), 256, 0, stream>>>(p, Ssum, C, S);
    finalize_stats<<<dim3((4 * C + 255) / 256), 256, 0, stream>>>(
        Ssum, S_mean, S_rstd, 4 * C, 1.f / (float)S);
  };

  // conv0 (MFMA) -> A (raw); stats
  transform_w0<<<dim3((7 * 64 * 32 + 255) / 256), 256, 0, stream>>>(w0, WT0);
  transform_wf<<<dim3((49 * 16 * 64 + 255) / 256), 256, 0, stream>>>(wf, WTf);
  conv0_mfma<<<dim3(1024, 4), 256, 0, stream>>>(x, WT0, b0, A);
  STATS(A, 64, 512 * 512);

  // d0: A(64,512) -> B(128,256)
  XFORM(dw[0], WTp0, 64, 128, 0);
  down_mfma<<<dim3(1, 1024, 4), 256, 0, stream>>>(A, WTp0, db[0], S_mean, S_rstd, Bh, 64, 128, 512, 512);
  STATS(Bh, 128, 256 * 256);
  // d1: B -> A(256,128)
  XFORM(dw[1], WTA, 128, 256, 0);
  down_mfma<<<dim3(2, 256, 4), 256, 0, stream>>>(Bh, WTA, db[1], S_mean, S_rstd, A, 128, 256, 256, 256);
  STATS(A, 256, 128 * 128);
  // d2: A -> B(512,64)
  XFORM(dw[2], WTB, 256, 512, 0);
  down_mfma<<<dim3(4, 64, 4), 256, 0, stream>>>(A, WTB, db[2], S_mean, S_rstd, Bh, 256, 512, 128, 128);
  STATS(Bh, 512, 64 * 64);
  // d3: B -> A(1024,32)
  XFORM(dw[3], WTA, 512, 1024, 0);
  down_mfma<<<dim3(8, 16, 4), 256, 0, stream>>>(Bh, WTA, db[3], S_mean, S_rstd, A, 512, 1024, 64, 64);
  STATS(A, 1024, 32 * 32);

  // u0: A(1024,32) -> B(512,64)
  XFORM(uw[0], WTB, 1024, 512, 1);
  up_mfma<<<dim3(8, 16, 4), 256, 0, stream>>>(A, WTB, ub[0], S_mean, S_rstd, Bh, 1024, 512, 32, 32);
  STATS(Bh, 512, 64 * 64);
  // u1: B -> A(256,128)
  XFORM(uw[1], WTA, 512, 256, 1);
  up_mfma<<<dim3(4, 64, 4), 256, 0, stream>>>(Bh, WTA, ub[1], S_mean, S_rstd, A, 512, 256, 64, 64);
  STATS(A, 256, 128 * 128);
  // u2: A -> B(128,256)
  XFORM(uw[2], WTA, 256, 128, 1);
  up_mfma<<<dim3(2, 256, 4), 256, 0, stream>>>(A, WTA, ub[2], S_mean, S_rstd, Bh, 256, 128, 128, 128);
  STATS(Bh, 128, 256 * 256);
  // u3: B -> A(64,512)
  XFORM(uw[3], WTp1, 128, 64, 1);
  up_mfma<<<dim3(1, 1024, 4), 256, 0, stream>>>(Bh, WTp1, ub[3], S_mean, S_rstd, A, 128, 64, 256, 256);
  STATS(A, 64, 512 * 512);

  // final conv (MFMA) -> F (fp32 CHW), then pooling
  convf_mfma<<<dim3(1024, 4), 256, 0, stream>>>(A, WTf, bf, S_mean, S_rstd, F);
  hipMemsetAsync(P, 0, 16 * sizeof(float), stream);
  pool_sum_kernel<<<dim3(4, 32), 256, 0, stream>>>(F, inst, P);
  pool_scatter_kernel<<<dim3(4096), 256, 0, stream>>>(inst, P, (float*)d_out);
}